// Round 7
// baseline (591.948 us; speedup 1.0000x reference)
//
#include <hip/hip_runtime.h>

#define N_NODES 50000
#define N_EDGES 1600000
#define IN_F    512
#define OUT_F   256

typedef __attribute__((ext_vector_type(8))) short bf16x8;
typedef __attribute__((ext_vector_type(4))) float f32x4;

__device__ __forceinline__ short bf16rne(float f) {
    unsigned u = __builtin_bit_cast(unsigned, f);
    u += 0x7fffu + ((u >> 16) & 1u);          // round-to-nearest-even
    return (short)(u >> 16);
}

__device__ __forceinline__ float b2f(unsigned short h) {
    unsigned u = (unsigned)h << 16;
    return __builtin_bit_cast(float, u);
}

// ---------------------------------------------------------------------------
// Kernel 0: Wt[n][k] = bf16(W[k][n])  — transpose + convert weight (512x256)
// ---------------------------------------------------------------------------
__global__ __launch_bounds__(256) void wt_kernel(const float* __restrict__ W,
                                                 short* __restrict__ Wt) {
    int idx = blockIdx.x * 256 + threadIdx.x;
    if (idx < IN_F * OUT_F) {
        int n = idx >> 9;          // /512
        int k = idx & 511;
        Wt[idx] = bf16rne(W[(size_t)k * OUT_F + n]);
    }
}

// ---------------------------------------------------------------------------
// Kernel 1: support(bf16) = features @ weight via bf16 MFMA.
// BM=128, BN=256 (full N), BK=32. 8 waves (512 thr): wave-tile 64x64.
// ---------------------------------------------------------------------------
#define ASTRIDE 40
#define BSTRIDE 40

__global__ __launch_bounds__(512) void gemm_mfma_kernel(const float* __restrict__ A,
                                                        const short* __restrict__ Wt,
                                                        unsigned short* __restrict__ Cb) {
    __shared__ short As[128 * ASTRIDE];
    __shared__ short Bs[256 * BSTRIDE];

    const int tid  = threadIdx.x;
    const int wave = tid >> 6;
    const int lane = tid & 63;
    const int m0   = blockIdx.x * 128;
    const int wrow = (wave >> 2) * 64;       // 0 or 64
    const int wcol = (wave & 3) * 64;        // 0/64/128/192

    const int quad = lane >> 4;
    const int l16  = lane & 15;

    const int ar = tid >> 2;                 // 0..127 (A row within tile)
    const int aq = tid & 3;                  // 0..3   (8-wide k chunk)

    const int bn = tid >> 1;                 // 0..255 (B row = out col)
    const int bh = tid & 1;                  // 0..1   (16-wide k half)

    f32x4 zero4 = {0.f, 0.f, 0.f, 0.f};
    f32x4 acc[4][4];
#pragma unroll
    for (int i = 0; i < 4; ++i)
#pragma unroll
        for (int j = 0; j < 4; ++j) acc[i][j] = zero4;

    for (int k0 = 0; k0 < IN_F; k0 += 32) {
        {
            const int gm = m0 + ar;
            float4 v0 = make_float4(0.f, 0.f, 0.f, 0.f);
            float4 v1 = v0;
            if (gm < N_NODES) {
                const float* p = A + (size_t)gm * IN_F + k0 + aq * 8;
                v0 = *(const float4*)p;
                v1 = *(const float4*)(p + 4);
            }
            bf16x8 b;
            b[0] = bf16rne(v0.x); b[1] = bf16rne(v0.y);
            b[2] = bf16rne(v0.z); b[3] = bf16rne(v0.w);
            b[4] = bf16rne(v1.x); b[5] = bf16rne(v1.y);
            b[6] = bf16rne(v1.z); b[7] = bf16rne(v1.w);
            *(bf16x8*)&As[ar * ASTRIDE + aq * 8] = b;
        }
        {
            const short* src = Wt + (size_t)bn * IN_F + k0 + bh * 16;
            bf16x8 w0 = *(const bf16x8*)(src + 0);
            bf16x8 w1 = *(const bf16x8*)(src + 8);
            short* dst = &Bs[bn * BSTRIDE + bh * 16];
            *(bf16x8*)(dst + 0) = w0;
            *(bf16x8*)(dst + 8) = w1;
        }
        __syncthreads();

        bf16x8 af[4], bf[4];
#pragma unroll
        for (int mt = 0; mt < 4; ++mt)
            af[mt] = *(const bf16x8*)&As[(wrow + mt * 16 + l16) * ASTRIDE + quad * 8];
#pragma unroll
        for (int nt = 0; nt < 4; ++nt)
            bf[nt] = *(const bf16x8*)&Bs[(wcol + nt * 16 + l16) * BSTRIDE + quad * 8];

#pragma unroll
        for (int mt = 0; mt < 4; ++mt)
#pragma unroll
            for (int nt = 0; nt < 4; ++nt)
                acc[mt][nt] = __builtin_amdgcn_mfma_f32_16x16x32_bf16(
                    af[mt], bf[nt], acc[mt][nt], 0, 0, 0);
        __syncthreads();
    }

#pragma unroll
    for (int mt = 0; mt < 4; ++mt) {
        const int rbase = m0 + wrow + mt * 16 + quad * 4;
#pragma unroll
        for (int i = 0; i < 4; ++i) {
            const int row = rbase + i;
            if (row < N_NODES) {
#pragma unroll
                for (int nt = 0; nt < 4; ++nt)
                    Cb[(size_t)row * OUT_F + wcol + nt * 16 + l16] =
                        (unsigned short)bf16rne(acc[mt][nt][i]);
            }
        }
    }
}

// ---------------------------------------------------------------------------
// Direct edge grouping (replaces 5-kernel two-pass bucket sort):
//   zero 50K row counters -> global-atomic histogram -> 1-block scan
//   (excl + cursor) -> atomic-rank scatter into packed ecv records.
// Intra-row order is nondeterministic, same as the old sortB (LDS atomics);
// gather only needs row-grouped records.
// ---------------------------------------------------------------------------
__global__ __launch_bounds__(256) void zero_counts_kernel(int* __restrict__ rowCount) {
    int i = blockIdx.x * 256 + threadIdx.x;
    if (i < N_NODES) rowCount[i] = 0;
}

__global__ __launch_bounds__(256) void hist_kernel(const int* __restrict__ rows,
                                                   int* __restrict__ rowCount) {
    int i = blockIdx.x * 256 + threadIdx.x;
    if (i < N_EDGES) atomicAdd(&rowCount[rows[i]], 1);
}

#define SCAN_T 1024
#define CHUNK  ((N_NODES + SCAN_T - 1) / SCAN_T)   // 49 rows per thread

__global__ __launch_bounds__(SCAN_T) void scan_kernel(const int* __restrict__ rowCount,
                                                      int* __restrict__ excl,
                                                      int* __restrict__ cursor) {
    __shared__ int part[SCAN_T];
    const int t = threadIdx.x;
    const int base = t * CHUNK;

    int s = 0;
    for (int j = 0; j < CHUNK; ++j) {
        const int i = base + j;
        if (i < N_NODES) s += rowCount[i];
    }
    part[t] = s;
    for (int off = 1; off < SCAN_T; off <<= 1) {
        __syncthreads();
        int v = (t >= off) ? part[t - off] : 0;
        __syncthreads();
        part[t] += v;
    }
    __syncthreads();

    int run = (t > 0) ? part[t - 1] : 0;     // exclusive prefix of this chunk
    for (int j = 0; j < CHUNK; ++j) {
        const int i = base + j;
        if (i < N_NODES) {
            excl[i]   = run;
            cursor[i] = run;
            run += rowCount[i];
        }
    }
}

__global__ __launch_bounds__(256) void scatter_kernel(const int* __restrict__ rows,
                                                      const int* __restrict__ cols,
                                                      const float* __restrict__ vals,
                                                      int* __restrict__ cursor,
                                                      unsigned int* __restrict__ ecv) {
    int i = blockIdx.x * 256 + threadIdx.x;
    if (i < N_EDGES) {
        const int r   = rows[i];
        const int pos = atomicAdd(&cursor[r], 1);
        ecv[pos] = ((unsigned int)cols[i] << 16) |
                   (unsigned short)bf16rne(vals[i]);
    }
}

// ---------------------------------------------------------------------------
// Gather (R0 structure, best measured: ~105 us for full 50K rows).
// One wave per output row, support bf16 (ushort4/lane -> 512B/edge = 4 lines),
// packed 4B edge records, 4-edge unroll, fp32 accumulate, fused ReLU.
// Launched twice (25K rows each) for rocprof visibility; total work identical.
// ---------------------------------------------------------------------------
__global__ __launch_bounds__(256) void gather_kernel(const ushort4* __restrict__ support,
                                                     const int* __restrict__ excl,
                                                     const unsigned int* __restrict__ ecv,
                                                     float4* __restrict__ out,
                                                     int row0) {
    const int tid  = threadIdx.x;
    const int row  = row0 + blockIdx.x * 4 + (tid >> 6);
    const int lane = tid & 63;
    if (row >= N_NODES) return;

    const int start = excl[row];
    const int end   = (row + 1 < N_NODES) ? excl[row + 1] : N_EDGES;

    float4 acc = make_float4(0.f, 0.f, 0.f, 0.f);
    int e = start;
    const int end4 = start + ((end - start) & ~3);
    for (; e < end4; e += 4) {
        const unsigned int p0 = ecv[e];
        const unsigned int p1 = ecv[e + 1];
        const unsigned int p2 = ecv[e + 2];
        const unsigned int p3 = ecv[e + 3];
        const ushort4 s0 = support[(size_t)(p0 >> 16) * 64 + lane];
        const ushort4 s1 = support[(size_t)(p1 >> 16) * 64 + lane];
        const ushort4 s2 = support[(size_t)(p2 >> 16) * 64 + lane];
        const ushort4 s3 = support[(size_t)(p3 >> 16) * 64 + lane];
        const float v0 = b2f((unsigned short)(p0 & 0xFFFF));
        const float v1 = b2f((unsigned short)(p1 & 0xFFFF));
        const float v2 = b2f((unsigned short)(p2 & 0xFFFF));
        const float v3 = b2f((unsigned short)(p3 & 0xFFFF));
        acc.x += v0 * b2f(s0.x); acc.y += v0 * b2f(s0.y);
        acc.z += v0 * b2f(s0.z); acc.w += v0 * b2f(s0.w);
        acc.x += v1 * b2f(s1.x); acc.y += v1 * b2f(s1.y);
        acc.z += v1 * b2f(s1.z); acc.w += v1 * b2f(s1.w);
        acc.x += v2 * b2f(s2.x); acc.y += v2 * b2f(s2.y);
        acc.z += v2 * b2f(s2.z); acc.w += v2 * b2f(s2.w);
        acc.x += v3 * b2f(s3.x); acc.y += v3 * b2f(s3.y);
        acc.z += v3 * b2f(s3.z); acc.w += v3 * b2f(s3.w);
    }
    for (; e < end; ++e) {
        const unsigned int p0 = ecv[e];
        const ushort4 s0 = support[(size_t)(p0 >> 16) * 64 + lane];
        const float v0 = b2f((unsigned short)(p0 & 0xFFFF));
        acc.x += v0 * b2f(s0.x); acc.y += v0 * b2f(s0.y);
        acc.z += v0 * b2f(s0.z); acc.w += v0 * b2f(s0.w);
    }

    acc.x = fmaxf(acc.x, 0.f);
    acc.y = fmaxf(acc.y, 0.f);
    acc.z = fmaxf(acc.z, 0.f);
    acc.w = fmaxf(acc.w, 0.f);
    out[(size_t)row * 64 + lane] = acc;
}

extern "C" void kernel_launch(void* const* d_in, const int* in_sizes, int n_in,
                              void* d_out, int out_size, void* d_ws, size_t ws_size,
                              hipStream_t stream) {
    const float* features  = (const float*)d_in[0];   // [50000, 512]
    const float* weight    = (const float*)d_in[1];   // [512, 256]
    const float* edge_vals = (const float*)d_in[2];   // [1.6M]
    const int*   edge_rows = (const int*)d_in[3];
    const int*   edge_cols = (const int*)d_in[4];
    float* out = (float*)d_out;                       // [50000, 256]

    // workspace layout (8B-aligned chunks first)
    unsigned short* support_bf = (unsigned short*)d_ws;                 // 25.6 MB
    unsigned int* ecv = (unsigned int*)(support_bf + (size_t)N_NODES * OUT_F); // 6.4 MB
    int*   excl      = (int*)(ecv + N_EDGES);                           // 50000
    int*   cursor    = excl + N_NODES;                                  // 50000
    int*   rowCount  = cursor + N_NODES;                                // 50000
    short* Wt        = (short*)(rowCount + N_NODES);                    // 131072 bf16

    // 1) weight transpose + bf16 convert
    wt_kernel<<<(IN_F * OUT_F + 255) / 256, 256, 0, stream>>>(weight, Wt);

    // 2) MFMA GEMM: support(bf16) = features @ weight (BM=128, 8 waves)
    gemm_mfma_kernel<<<(N_NODES + 127) / 128, 512, 0, stream>>>(features, Wt, support_bf);

    // 3) direct edge grouping: hist -> scan -> scatter
    zero_counts_kernel<<<(N_NODES + 255) / 256, 256, 0, stream>>>(rowCount);
    hist_kernel<<<(N_EDGES + 255) / 256, 256, 0, stream>>>(edge_rows, rowCount);
    scan_kernel<<<1, SCAN_T, 0, stream>>>(rowCount, excl, cursor);
    scatter_kernel<<<(N_EDGES + 255) / 256, 256, 0, stream>>>(edge_rows, edge_cols,
                                                              edge_vals, cursor, ecv);

    // 4) gather + fused ReLU (one wave per row), split into 2 dispatches
    gather_kernel<<<25000 / 4, 256, 0, stream>>>(
        (const ushort4*)support_bf, excl, ecv, (float4*)out, 0);
    gather_kernel<<<25000 / 4, 256, 0, stream>>>(
        (const ushort4*)support_bf, excl, ecv, (float4*)out, 25000);
}

// Round 8
// 369.361 us; speedup vs baseline: 1.6026x; 1.6026x over previous
//
#include <hip/hip_runtime.h>

#define N_NODES 50000
#define N_EDGES 1600000
#define IN_F    512
#define OUT_F   256

// two-pass sort params: fine buckets of 128 rows
#define BROWS   128
#define NBINS   ((N_NODES + BROWS - 1) / BROWS)    // 391
#define BATCH   2048
#define NBATCHES ((N_EDGES + BATCH - 1) / BATCH)   // 782

typedef __attribute__((ext_vector_type(8))) short bf16x8;
typedef __attribute__((ext_vector_type(4))) float f32x4;

__device__ __forceinline__ short bf16rne(float f) {
    unsigned u = __builtin_bit_cast(unsigned, f);
    u += 0x7fffu + ((u >> 16) & 1u);          // round-to-nearest-even
    return (short)(u >> 16);
}

__device__ __forceinline__ float b2f(unsigned short h) {
    unsigned u = (unsigned)h << 16;
    return __builtin_bit_cast(float, u);
}

// ---------------------------------------------------------------------------
// Kernel 0: Wt[n][k] = bf16(W[k][n])  — transpose + convert weight (512x256)
// ---------------------------------------------------------------------------
__global__ __launch_bounds__(256) void wt_kernel(const float* __restrict__ W,
                                                 short* __restrict__ Wt) {
    int idx = blockIdx.x * 256 + threadIdx.x;
    if (idx < IN_F * OUT_F) {
        int n = idx >> 9;          // /512
        int k = idx & 511;
        Wt[idx] = bf16rne(W[(size_t)k * OUT_F + n]);
    }
}

// ---------------------------------------------------------------------------
// Kernel 1: support(bf16) = features @ weight via bf16 MFMA.
// BM=128, BN=256 (full N), BK=32. 8 waves (512 thr): wave-tile 64x64.
// ---------------------------------------------------------------------------
#define ASTRIDE 40
#define BSTRIDE 40

__global__ __launch_bounds__(512) void gemm_mfma_kernel(const float* __restrict__ A,
                                                        const short* __restrict__ Wt,
                                                        unsigned short* __restrict__ Cb) {
    __shared__ short As[128 * ASTRIDE];
    __shared__ short Bs[256 * BSTRIDE];

    const int tid  = threadIdx.x;
    const int wave = tid >> 6;
    const int lane = tid & 63;
    const int m0   = blockIdx.x * 128;
    const int wrow = (wave >> 2) * 64;       // 0 or 64
    const int wcol = (wave & 3) * 64;        // 0/64/128/192

    const int quad = lane >> 4;
    const int l16  = lane & 15;

    const int ar = tid >> 2;                 // 0..127 (A row within tile)
    const int aq = tid & 3;                  // 0..3   (8-wide k chunk)

    const int bn = tid >> 1;                 // 0..255 (B row = out col)
    const int bh = tid & 1;                  // 0..1   (16-wide k half)

    f32x4 zero4 = {0.f, 0.f, 0.f, 0.f};
    f32x4 acc[4][4];
#pragma unroll
    for (int i = 0; i < 4; ++i)
#pragma unroll
        for (int j = 0; j < 4; ++j) acc[i][j] = zero4;

    for (int k0 = 0; k0 < IN_F; k0 += 32) {
        {
            const int gm = m0 + ar;
            float4 v0 = make_float4(0.f, 0.f, 0.f, 0.f);
            float4 v1 = v0;
            if (gm < N_NODES) {
                const float* p = A + (size_t)gm * IN_F + k0 + aq * 8;
                v0 = *(const float4*)p;
                v1 = *(const float4*)(p + 4);
            }
            bf16x8 b;
            b[0] = bf16rne(v0.x); b[1] = bf16rne(v0.y);
            b[2] = bf16rne(v0.z); b[3] = bf16rne(v0.w);
            b[4] = bf16rne(v1.x); b[5] = bf16rne(v1.y);
            b[6] = bf16rne(v1.z); b[7] = bf16rne(v1.w);
            *(bf16x8*)&As[ar * ASTRIDE + aq * 8] = b;
        }
        {
            const short* src = Wt + (size_t)bn * IN_F + k0 + bh * 16;
            bf16x8 w0 = *(const bf16x8*)(src + 0);
            bf16x8 w1 = *(const bf16x8*)(src + 8);
            short* dst = &Bs[bn * BSTRIDE + bh * 16];
            *(bf16x8*)(dst + 0) = w0;
            *(bf16x8*)(dst + 8) = w1;
        }
        __syncthreads();

        bf16x8 af[4], bf[4];
#pragma unroll
        for (int mt = 0; mt < 4; ++mt)
            af[mt] = *(const bf16x8*)&As[(wrow + mt * 16 + l16) * ASTRIDE + quad * 8];
#pragma unroll
        for (int nt = 0; nt < 4; ++nt)
            bf[nt] = *(const bf16x8*)&Bs[(wcol + nt * 16 + l16) * BSTRIDE + quad * 8];

#pragma unroll
        for (int mt = 0; mt < 4; ++mt)
#pragma unroll
            for (int nt = 0; nt < 4; ++nt)
                acc[mt][nt] = __builtin_amdgcn_mfma_f32_16x16x32_bf16(
                    af[mt], bf[nt], acc[mt][nt], 0, 0, 0);
        __syncthreads();
    }

#pragma unroll
    for (int mt = 0; mt < 4; ++mt) {
        const int rbase = m0 + wrow + mt * 16 + quad * 4;
#pragma unroll
        for (int i = 0; i < 4; ++i) {
            const int row = rbase + i;
            if (row < N_NODES) {
#pragma unroll
                for (int nt = 0; nt < 4; ++nt)
                    Cb[(size_t)row * OUT_F + wcol + nt * 16 + l16] =
                        (unsigned short)bf16rne(acc[mt][nt][i]);
            }
        }
    }
}

// ---------------------------------------------------------------------------
// Two-pass edge sort (391 buckets x 128 rows).
// Pass A: coarse bin by row>>7, LDS-staged for contiguous bucket runs.
//         binned entry: x = (row&127)<<16 | col, y = fp32 val bits.
// Pass B: per-bucket counting sort over 128 local rows; emits global excl and
//         packed 4B edge records: (col<<16) | bf16(val).
// (R7 lesson: direct hist+scan+scatter is strictly worse — single-block scan
//  is latency-bound 129us and random 4B scatter beats nothing; the LDS-staged
//  two-pass exists precisely to make writes bucket-contiguous.)
// ---------------------------------------------------------------------------
__global__ __launch_bounds__(256) void zero_bins_kernel(int* __restrict__ binCounts) {
    int i = blockIdx.x * 256 + threadIdx.x;
    if (i < NBINS) binCounts[i] = 0;
}

__global__ __launch_bounds__(256) void histA_kernel(const int* __restrict__ rows,
                                                    int* __restrict__ binCounts) {
    __shared__ int lh[NBINS];
    const int tid = threadIdx.x;
    for (int i = tid; i < NBINS; i += 256) lh[i] = 0;
    __syncthreads();
    for (int i = blockIdx.x * 256 + tid; i < N_EDGES; i += gridDim.x * 256)
        atomicAdd(&lh[rows[i] >> 7], 1);
    __syncthreads();
    for (int i = tid; i < NBINS; i += 256)
        if (lh[i]) atomicAdd(&binCounts[i], lh[i]);
}

// exclusive scan of 391 bin counts (pair-scan, 512 padded, 256 threads)
__global__ __launch_bounds__(256) void scanA_kernel(const int* __restrict__ binCounts,
                                                    int* __restrict__ binStart,
                                                    int* __restrict__ gcursor) {
    __shared__ int stmp[256];
    const int tid = threadIdx.x;
    const int i0 = 2 * tid, i1 = 2 * tid + 1;
    const int a0 = (i0 < NBINS) ? binCounts[i0] : 0;
    const int a1 = (i1 < NBINS) ? binCounts[i1] : 0;
    const int pair = a0 + a1;
    stmp[tid] = pair;
    for (int off = 1; off < 256; off <<= 1) {
        __syncthreads();
        int t = (tid >= off) ? stmp[tid - off] : 0;
        __syncthreads();
        stmp[tid] += t;
    }
    __syncthreads();
    const int pexcl = stmp[tid] - pair;
    if (i0 < NBINS) { binStart[i0] = pexcl;      gcursor[i0] = pexcl; }
    if (i1 < NBINS) { binStart[i1] = pexcl + a0; gcursor[i1] = pexcl + a0; }
}

__global__ __launch_bounds__(256) void fillA_kernel(const int* __restrict__ rows,
                                                    const int* __restrict__ cols,
                                                    const float* __restrict__ vals,
                                                    int* __restrict__ gcursor,
                                                    int2* __restrict__ binned) {
    __shared__ int lhist[NBINS];
    __shared__ int lexcl[NBINS];
    __shared__ int gbase[NBINS];
    __shared__ int stmp[256];
    __shared__ int2 lstage[BATCH];
    __shared__ unsigned short sbucket[BATCH];

    const int tid   = threadIdx.x;
    const int start = blockIdx.x * BATCH;
    const int count = min(BATCH, N_EDGES - start);

    for (int i = tid; i < NBINS; i += 256) lhist[i] = 0;
    __syncthreads();

    int myrow[8], myrank[8];
#pragma unroll
    for (int j = 0; j < 8; ++j) {
        const int s = j * 256 + tid;
        if (s < count) {
            const int r = rows[start + s];
            myrow[j]  = r;
            myrank[j] = atomicAdd(&lhist[r >> 7], 1);
        }
    }
    __syncthreads();

    // pair-scan of lhist (391 -> 512 padded) + reserve global space per bucket
    {
        const int i0 = 2 * tid, i1 = 2 * tid + 1;
        const int a0 = (i0 < NBINS) ? lhist[i0] : 0;
        const int a1 = (i1 < NBINS) ? lhist[i1] : 0;
        const int pair = a0 + a1;
        stmp[tid] = pair;
        for (int off = 1; off < 256; off <<= 1) {
            __syncthreads();
            int t = (tid >= off) ? stmp[tid - off] : 0;
            __syncthreads();
            stmp[tid] += t;
        }
        __syncthreads();
        const int pexcl = stmp[tid] - pair;
        if (i0 < NBINS) {
            lexcl[i0] = pexcl;
            gbase[i0] = a0 ? atomicAdd(&gcursor[i0], a0) : 0;
        }
        if (i1 < NBINS) {
            lexcl[i1] = pexcl + a0;
            gbase[i1] = a1 ? atomicAdd(&gcursor[i1], a1) : 0;
        }
    }
    __syncthreads();

    // stage into LDS ordered by bucket
#pragma unroll
    for (int j = 0; j < 8; ++j) {
        const int s = j * 256 + tid;
        if (s < count) {
            const int r   = myrow[j];
            const int b   = r >> 7;
            const int pos = lexcl[b] + myrank[j];
            lstage[pos]  = make_int2(((r & 127) << 16) | cols[start + s],
                                     __float_as_int(vals[start + s]));
            sbucket[pos] = (unsigned short)b;
        }
    }
    __syncthreads();

    // write out: bucket runs contiguous
#pragma unroll
    for (int j = 0; j < 8; ++j) {
        const int s = j * 256 + tid;
        if (s < count) {
            const int b = sbucket[s];
            binned[gbase[b] + (s - lexcl[b])] = lstage[s];
        }
    }
}

__global__ __launch_bounds__(256) void sortB_kernel(const int2* __restrict__ binned,
                                                    const int* __restrict__ binStart,
                                                    const int* __restrict__ binCounts,
                                                    int* __restrict__ excl,
                                                    unsigned int* __restrict__ ecv) {
    __shared__ int lhist[BROWS];
    __shared__ int lcur[BROWS];

    const int tid  = threadIdx.x;
    const int b    = blockIdx.x;
    const int base = binStart[b];
    const int cnt  = binCounts[b];

    if (tid < BROWS) lhist[tid] = 0;
    __syncthreads();

    for (int i = tid; i < cnt; i += 256)
        atomicAdd(&lhist[binned[base + i].x >> 16], 1);
    __syncthreads();

    // scan 128 with first 128 threads (Hillis-Steele in lcur as temp)
    if (tid < BROWS) lcur[tid] = lhist[tid];
    for (int off = 1; off < BROWS; off <<= 1) {
        __syncthreads();
        int t = (tid >= off && tid < BROWS) ? lcur[tid - off] : 0;
        __syncthreads();
        if (tid < BROWS) lcur[tid] += t;
    }
    __syncthreads();
    if (tid < BROWS) {
        const int pexcl = lcur[tid] - lhist[tid];
        const int row   = b * BROWS + tid;
        lcur[tid] = pexcl;
        if (row < N_NODES) excl[row] = base + pexcl;
    }
    __syncthreads();

    for (int i = tid; i < cnt; i += 256) {
        const int2 e  = binned[base + i];
        const int rl  = e.x >> 16;
        const int col = e.x & 0xFFFF;
        const int rank = atomicAdd(&lcur[rl], 1);
        ecv[base + rank] = ((unsigned int)col << 16) |
                           (unsigned short)bf16rne(__int_as_float(e.y));
    }
}

// ---------------------------------------------------------------------------
// Gather (R0 structure, measured ~105 us for 50K rows — structural floor for
// bf16 support: 4 x 128B lines/edge at ~10 cy/line/CU request throughput).
// One wave per output row, packed 4B edge records, 4-edge unroll, fp32
// accumulate, fused ReLU.
// ---------------------------------------------------------------------------
__global__ __launch_bounds__(256) void gather_kernel(const ushort4* __restrict__ support,
                                                     const int* __restrict__ excl,
                                                     const unsigned int* __restrict__ ecv,
                                                     float4* __restrict__ out) {
    const int tid  = threadIdx.x;
    const int row  = blockIdx.x * 4 + (tid >> 6);
    const int lane = tid & 63;
    if (row >= N_NODES) return;

    const int start = excl[row];
    const int end   = (row + 1 < N_NODES) ? excl[row + 1] : N_EDGES;

    float4 acc = make_float4(0.f, 0.f, 0.f, 0.f);
    int e = start;
    const int end4 = start + ((end - start) & ~3);
    for (; e < end4; e += 4) {
        const unsigned int p0 = ecv[e];
        const unsigned int p1 = ecv[e + 1];
        const unsigned int p2 = ecv[e + 2];
        const unsigned int p3 = ecv[e + 3];
        const ushort4 s0 = support[(size_t)(p0 >> 16) * 64 + lane];
        const ushort4 s1 = support[(size_t)(p1 >> 16) * 64 + lane];
        const ushort4 s2 = support[(size_t)(p2 >> 16) * 64 + lane];
        const ushort4 s3 = support[(size_t)(p3 >> 16) * 64 + lane];
        const float v0 = b2f((unsigned short)(p0 & 0xFFFF));
        const float v1 = b2f((unsigned short)(p1 & 0xFFFF));
        const float v2 = b2f((unsigned short)(p2 & 0xFFFF));
        const float v3 = b2f((unsigned short)(p3 & 0xFFFF));
        acc.x += v0 * b2f(s0.x); acc.y += v0 * b2f(s0.y);
        acc.z += v0 * b2f(s0.z); acc.w += v0 * b2f(s0.w);
        acc.x += v1 * b2f(s1.x); acc.y += v1 * b2f(s1.y);
        acc.z += v1 * b2f(s1.z); acc.w += v1 * b2f(s1.w);
        acc.x += v2 * b2f(s2.x); acc.y += v2 * b2f(s2.y);
        acc.z += v2 * b2f(s2.z); acc.w += v2 * b2f(s2.w);
        acc.x += v3 * b2f(s3.x); acc.y += v3 * b2f(s3.y);
        acc.z += v3 * b2f(s3.z); acc.w += v3 * b2f(s3.w);
    }
    for (; e < end; ++e) {
        const unsigned int p0 = ecv[e];
        const ushort4 s0 = support[(size_t)(p0 >> 16) * 64 + lane];
        const float v0 = b2f((unsigned short)(p0 & 0xFFFF));
        acc.x += v0 * b2f(s0.x); acc.y += v0 * b2f(s0.y);
        acc.z += v0 * b2f(s0.z); acc.w += v0 * b2f(s0.w);
    }

    acc.x = fmaxf(acc.x, 0.f);
    acc.y = fmaxf(acc.y, 0.f);
    acc.z = fmaxf(acc.z, 0.f);
    acc.w = fmaxf(acc.w, 0.f);
    out[(size_t)row * 64 + lane] = acc;
}

extern "C" void kernel_launch(void* const* d_in, const int* in_sizes, int n_in,
                              void* d_out, int out_size, void* d_ws, size_t ws_size,
                              hipStream_t stream) {
    const float* features  = (const float*)d_in[0];   // [50000, 512]
    const float* weight    = (const float*)d_in[1];   // [512, 256]
    const float* edge_vals = (const float*)d_in[2];   // [1.6M]
    const int*   edge_rows = (const int*)d_in[3];
    const int*   edge_cols = (const int*)d_in[4];
    float* out = (float*)d_out;                       // [50000, 256]

    // workspace layout (8B-aligned chunks first)
    unsigned short* support_bf = (unsigned short*)d_ws;                 // 25.6 MB
    int2*  binned    = (int2*)(support_bf + (size_t)N_NODES * OUT_F);   // 12.8 MB
    unsigned int* ecv = (unsigned int*)(binned + N_EDGES);              // 6.4 MB
    int*   excl      = (int*)(ecv + N_EDGES);                           // 50000
    int*   binCounts = excl + N_NODES;                                  // 512
    int*   binStart  = binCounts + 512;                                 // 512
    int*   gcursor   = binStart + 512;                                  // 512
    short* Wt        = (short*)(gcursor + 512);                         // 131072 bf16

    // 1) weight transpose + bf16 convert
    wt_kernel<<<(IN_F * OUT_F + 255) / 256, 256, 0, stream>>>(weight, Wt);

    // 2) MFMA GEMM: support(bf16) = features @ weight (BM=128, 8 waves)
    gemm_mfma_kernel<<<(N_NODES + 127) / 128, 512, 0, stream>>>(features, Wt, support_bf);

    // 3) two-pass edge sort
    zero_bins_kernel<<<2, 256, 0, stream>>>(binCounts);
    histA_kernel<<<256, 256, 0, stream>>>(edge_rows, binCounts);
    scanA_kernel<<<1, 256, 0, stream>>>(binCounts, binStart, gcursor);
    fillA_kernel<<<NBATCHES, 256, 0, stream>>>(edge_rows, edge_cols, edge_vals,
                                               gcursor, binned);
    sortB_kernel<<<NBINS, 256, 0, stream>>>(binned, binStart, binCounts, excl, ecv);

    // 4) gather + fused ReLU (one wave per row, no atomics)
    gather_kernel<<<(N_NODES + 3) / 4, 256, 0, stream>>>(
        (const ushort4*)support_bf, excl, ecv, (float4*)out);
}

// Round 9
// 353.241 us; speedup vs baseline: 1.6758x; 1.0456x over previous
//
#include <hip/hip_runtime.h>

#define N_NODES 50000
#define N_EDGES 1600000
#define IN_F    512
#define OUT_F   256

// two-pass sort params: fine buckets of 128 rows
#define BROWS   128
#define NBINS   ((N_NODES + BROWS - 1) / BROWS)    // 391
#define BATCH   4096
#define NBATCHES ((N_EDGES + BATCH - 1) / BATCH)   // 391
#define EPT     (BATCH / 256)                      // 16 edges per thread

typedef __attribute__((ext_vector_type(8))) short bf16x8;
typedef __attribute__((ext_vector_type(4))) float f32x4;
typedef unsigned long long ull;

__device__ __forceinline__ short bf16rne(float f) {
    unsigned u = __builtin_bit_cast(unsigned, f);
    u += 0x7fffu + ((u >> 16) & 1u);          // round-to-nearest-even
    return (short)(u >> 16);
}

__device__ __forceinline__ float b2f(unsigned short h) {
    unsigned u = (unsigned)h << 16;
    return __builtin_bit_cast(float, u);
}

// ---------------------------------------------------------------------------
// Kernel 0: Wt[n][k] = bf16(W[k][n])  — transpose + convert weight (512x256)
// ---------------------------------------------------------------------------
__global__ __launch_bounds__(256) void wt_kernel(const float* __restrict__ W,
                                                 short* __restrict__ Wt) {
    int idx = blockIdx.x * 256 + threadIdx.x;
    if (idx < IN_F * OUT_F) {
        int n = idx >> 9;          // /512
        int k = idx & 511;
        Wt[idx] = bf16rne(W[(size_t)k * OUT_F + n]);
    }
}

// ---------------------------------------------------------------------------
// Kernel 1: support(bf16) = features @ weight via bf16 MFMA.
// BM=128, BN=256 (full N), BK=32. 8 waves (512 thr): wave-tile 64x64.
// ---------------------------------------------------------------------------
#define ASTRIDE 40
#define BSTRIDE 40

__global__ __launch_bounds__(512) void gemm_mfma_kernel(const float* __restrict__ A,
                                                        const short* __restrict__ Wt,
                                                        unsigned short* __restrict__ Cb) {
    __shared__ short As[128 * ASTRIDE];
    __shared__ short Bs[256 * BSTRIDE];

    const int tid  = threadIdx.x;
    const int wave = tid >> 6;
    const int lane = tid & 63;
    const int m0   = blockIdx.x * 128;
    const int wrow = (wave >> 2) * 64;       // 0 or 64
    const int wcol = (wave & 3) * 64;        // 0/64/128/192

    const int quad = lane >> 4;
    const int l16  = lane & 15;

    const int ar = tid >> 2;                 // 0..127 (A row within tile)
    const int aq = tid & 3;                  // 0..3   (8-wide k chunk)

    const int bn = tid >> 1;                 // 0..255 (B row = out col)
    const int bh = tid & 1;                  // 0..1   (16-wide k half)

    f32x4 zero4 = {0.f, 0.f, 0.f, 0.f};
    f32x4 acc[4][4];
#pragma unroll
    for (int i = 0; i < 4; ++i)
#pragma unroll
        for (int j = 0; j < 4; ++j) acc[i][j] = zero4;

    for (int k0 = 0; k0 < IN_F; k0 += 32) {
        {
            const int gm = m0 + ar;
            float4 v0 = make_float4(0.f, 0.f, 0.f, 0.f);
            float4 v1 = v0;
            if (gm < N_NODES) {
                const float* p = A + (size_t)gm * IN_F + k0 + aq * 8;
                v0 = *(const float4*)p;
                v1 = *(const float4*)(p + 4);
            }
            bf16x8 b;
            b[0] = bf16rne(v0.x); b[1] = bf16rne(v0.y);
            b[2] = bf16rne(v0.z); b[3] = bf16rne(v0.w);
            b[4] = bf16rne(v1.x); b[5] = bf16rne(v1.y);
            b[6] = bf16rne(v1.z); b[7] = bf16rne(v1.w);
            *(bf16x8*)&As[ar * ASTRIDE + aq * 8] = b;
        }
        {
            const short* src = Wt + (size_t)bn * IN_F + k0 + bh * 16;
            bf16x8 w0 = *(const bf16x8*)(src + 0);
            bf16x8 w1 = *(const bf16x8*)(src + 8);
            short* dst = &Bs[bn * BSTRIDE + bh * 16];
            *(bf16x8*)(dst + 0) = w0;
            *(bf16x8*)(dst + 8) = w1;
        }
        __syncthreads();

        bf16x8 af[4], bf[4];
#pragma unroll
        for (int mt = 0; mt < 4; ++mt)
            af[mt] = *(const bf16x8*)&As[(wrow + mt * 16 + l16) * ASTRIDE + quad * 8];
#pragma unroll
        for (int nt = 0; nt < 4; ++nt)
            bf[nt] = *(const bf16x8*)&Bs[(wcol + nt * 16 + l16) * BSTRIDE + quad * 8];

#pragma unroll
        for (int mt = 0; mt < 4; ++mt)
#pragma unroll
            for (int nt = 0; nt < 4; ++nt)
                acc[mt][nt] = __builtin_amdgcn_mfma_f32_16x16x32_bf16(
                    af[mt], bf[nt], acc[mt][nt], 0, 0, 0);
        __syncthreads();
    }

#pragma unroll
    for (int mt = 0; mt < 4; ++mt) {
        const int rbase = m0 + wrow + mt * 16 + quad * 4;
#pragma unroll
        for (int i = 0; i < 4; ++i) {
            const int row = rbase + i;
            if (row < N_NODES) {
#pragma unroll
                for (int nt = 0; nt < 4; ++nt)
                    Cb[(size_t)row * OUT_F + wcol + nt * 16 + l16] =
                        (unsigned short)bf16rne(acc[mt][nt][i]);
            }
        }
    }
}

// ---------------------------------------------------------------------------
// Two-pass edge sort (391 buckets x 128 rows), consolidated (R9):
//  - zero: binCounts + relCur
//  - histA: global bucket histogram (LDS-staged atomics)
//  - fillA: DUAL scan (global binCounts prefix + local hist prefix packed in
//    one u64 Hillis-Steele — low field <= BATCH so no carry), block 0
//    publishes binStart; per-bucket space reserved via relCur atomics.
//    BATCH=4096 halves block count & fixed costs vs 2048. (scanA deleted.)
//  - sortB: 512 threads (halves serial strided loop over ~4092 edges/bucket)
// (R7 lesson: direct hist+scan+scatter is strictly worse; keep LDS staging.)
// ---------------------------------------------------------------------------
__global__ __launch_bounds__(256) void zero_bins_kernel(int* __restrict__ binCounts,
                                                        int* __restrict__ relCur) {
    int i = blockIdx.x * 256 + threadIdx.x;
    if (i < NBINS) { binCounts[i] = 0; relCur[i] = 0; }
}

__global__ __launch_bounds__(256) void histA_kernel(const int* __restrict__ rows,
                                                    int* __restrict__ binCounts) {
    __shared__ int lh[NBINS];
    const int tid = threadIdx.x;
    for (int i = tid; i < NBINS; i += 256) lh[i] = 0;
    __syncthreads();
    for (int i = blockIdx.x * 256 + tid; i < N_EDGES; i += gridDim.x * 256)
        atomicAdd(&lh[rows[i] >> 7], 1);
    __syncthreads();
    for (int i = tid; i < NBINS; i += 256)
        if (lh[i]) atomicAdd(&binCounts[i], lh[i]);
}

__global__ __launch_bounds__(256) void fillA_kernel(const int* __restrict__ rows,
                                                    const int* __restrict__ cols,
                                                    const float* __restrict__ vals,
                                                    const int* __restrict__ binCounts,
                                                    int* __restrict__ relCur,
                                                    int* __restrict__ binStart,
                                                    int2* __restrict__ binned) {
    __shared__ int lhist[NBINS];
    __shared__ int lexcl[NBINS];
    __shared__ int gbase[NBINS];
    __shared__ ull stmp2[256];
    __shared__ int2 lstage[BATCH];
    __shared__ unsigned short sbucket[BATCH];

    const int tid   = threadIdx.x;
    const int start = blockIdx.x * BATCH;
    const int count = min(BATCH, N_EDGES - start);

    for (int i = tid; i < NBINS; i += 256) lhist[i] = 0;
    __syncthreads();

    int myrow[EPT], myrank[EPT];
#pragma unroll
    for (int j = 0; j < EPT; ++j) {
        const int s = j * 256 + tid;
        if (s < count) {
            const int r = rows[start + s];
            myrow[j]  = r;
            myrank[j] = atomicAdd(&lhist[r >> 7], 1);
        }
    }
    __syncthreads();

    // dual pair-scan: high 32b = binCounts prefix (global), low 32b = lhist
    // prefix (local). Low total <= BATCH so no carry into high field.
    {
        const int i0 = 2 * tid, i1 = 2 * tid + 1;
        const int h0 = (i0 < NBINS) ? lhist[i0] : 0;
        const int h1 = (i1 < NBINS) ? lhist[i1] : 0;
        const int c0 = (i0 < NBINS) ? binCounts[i0] : 0;
        const int c1 = (i1 < NBINS) ? binCounts[i1] : 0;
        const ull pair = ((ull)(unsigned)(c0 + c1) << 32) | (unsigned)(h0 + h1);
        stmp2[tid] = pair;
        for (int off = 1; off < 256; off <<= 1) {
            __syncthreads();
            ull t = (tid >= off) ? stmp2[tid - off] : 0ull;
            __syncthreads();
            stmp2[tid] += t;
        }
        __syncthreads();
        const ull pex  = stmp2[tid] - pair;
        const int lex0 = (int)(pex & 0xffffffffull);
        const int bst0 = (int)(pex >> 32);
        if (i0 < NBINS) {
            lexcl[i0] = lex0;
            gbase[i0] = bst0 + (h0 ? atomicAdd(&relCur[i0], h0) : 0);
            if (blockIdx.x == 0) binStart[i0] = bst0;
        }
        if (i1 < NBINS) {
            lexcl[i1] = lex0 + h0;
            gbase[i1] = (bst0 + c0) + (h1 ? atomicAdd(&relCur[i1], h1) : 0);
            if (blockIdx.x == 0) binStart[i1] = bst0 + c0;
        }
    }
    __syncthreads();

    // stage into LDS ordered by bucket
#pragma unroll
    for (int j = 0; j < EPT; ++j) {
        const int s = j * 256 + tid;
        if (s < count) {
            const int r   = myrow[j];
            const int b   = r >> 7;
            const int pos = lexcl[b] + myrank[j];
            lstage[pos]  = make_int2(((r & 127) << 16) | cols[start + s],
                                     __float_as_int(vals[start + s]));
            sbucket[pos] = (unsigned short)b;
        }
    }
    __syncthreads();

    // write out: bucket runs contiguous
#pragma unroll
    for (int j = 0; j < EPT; ++j) {
        const int s = j * 256 + tid;
        if (s < count) {
            const int b = sbucket[s];
            binned[gbase[b] + (s - lexcl[b])] = lstage[s];
        }
    }
}

__global__ __launch_bounds__(512) void sortB_kernel(const int2* __restrict__ binned,
                                                    const int* __restrict__ binStart,
                                                    const int* __restrict__ binCounts,
                                                    int* __restrict__ excl,
                                                    unsigned int* __restrict__ ecv) {
    __shared__ int lhist[BROWS];
    __shared__ int lcur[BROWS];

    const int tid  = threadIdx.x;
    const int b    = blockIdx.x;
    const int base = binStart[b];
    const int cnt  = binCounts[b];

    if (tid < BROWS) lhist[tid] = 0;
    __syncthreads();

    for (int i = tid; i < cnt; i += 512)
        atomicAdd(&lhist[binned[base + i].x >> 16], 1);
    __syncthreads();

    // scan 128 with first 128 threads (Hillis-Steele in lcur as temp)
    if (tid < BROWS) lcur[tid] = lhist[tid];
    for (int off = 1; off < BROWS; off <<= 1) {
        __syncthreads();
        int t = (tid >= off && tid < BROWS) ? lcur[tid - off] : 0;
        __syncthreads();
        if (tid < BROWS) lcur[tid] += t;
    }
    __syncthreads();
    if (tid < BROWS) {
        const int pexcl = lcur[tid] - lhist[tid];
        const int row   = b * BROWS + tid;
        lcur[tid] = pexcl;
        if (row < N_NODES) excl[row] = base + pexcl;
    }
    __syncthreads();

    for (int i = tid; i < cnt; i += 512) {
        const int2 e  = binned[base + i];
        const int rl  = e.x >> 16;
        const int col = e.x & 0xFFFF;
        const int rank = atomicAdd(&lcur[rl], 1);
        ecv[base + rank] = ((unsigned int)col << 16) |
                           (unsigned short)bf16rne(__int_as_float(e.y));
    }
}

// ---------------------------------------------------------------------------
// Gather (R0 structure, measured ~105 us for 50K rows — structural floor for
// bf16 support: 4 x 128B lines/edge at ~10 cy/line/CU request throughput).
// One wave per output row, packed 4B edge records, 4-edge unroll, fp32
// accumulate, fused ReLU.
// ---------------------------------------------------------------------------
__global__ __launch_bounds__(256) void gather_kernel(const ushort4* __restrict__ support,
                                                     const int* __restrict__ excl,
                                                     const unsigned int* __restrict__ ecv,
                                                     float4* __restrict__ out) {
    const int tid  = threadIdx.x;
    const int row  = blockIdx.x * 4 + (tid >> 6);
    const int lane = tid & 63;
    if (row >= N_NODES) return;

    const int start = excl[row];
    const int end   = (row + 1 < N_NODES) ? excl[row + 1] : N_EDGES;

    float4 acc = make_float4(0.f, 0.f, 0.f, 0.f);
    int e = start;
    const int end4 = start + ((end - start) & ~3);
    for (; e < end4; e += 4) {
        const unsigned int p0 = ecv[e];
        const unsigned int p1 = ecv[e + 1];
        const unsigned int p2 = ecv[e + 2];
        const unsigned int p3 = ecv[e + 3];
        const ushort4 s0 = support[(size_t)(p0 >> 16) * 64 + lane];
        const ushort4 s1 = support[(size_t)(p1 >> 16) * 64 + lane];
        const ushort4 s2 = support[(size_t)(p2 >> 16) * 64 + lane];
        const ushort4 s3 = support[(size_t)(p3 >> 16) * 64 + lane];
        const float v0 = b2f((unsigned short)(p0 & 0xFFFF));
        const float v1 = b2f((unsigned short)(p1 & 0xFFFF));
        const float v2 = b2f((unsigned short)(p2 & 0xFFFF));
        const float v3 = b2f((unsigned short)(p3 & 0xFFFF));
        acc.x += v0 * b2f(s0.x); acc.y += v0 * b2f(s0.y);
        acc.z += v0 * b2f(s0.z); acc.w += v0 * b2f(s0.w);
        acc.x += v1 * b2f(s1.x); acc.y += v1 * b2f(s1.y);
        acc.z += v1 * b2f(s1.z); acc.w += v1 * b2f(s1.w);
        acc.x += v2 * b2f(s2.x); acc.y += v2 * b2f(s2.y);
        acc.z += v2 * b2f(s2.z); acc.w += v2 * b2f(s2.w);
        acc.x += v3 * b2f(s3.x); acc.y += v3 * b2f(s3.y);
        acc.z += v3 * b2f(s3.z); acc.w += v3 * b2f(s3.w);
    }
    for (; e < end; ++e) {
        const unsigned int p0 = ecv[e];
        const ushort4 s0 = support[(size_t)(p0 >> 16) * 64 + lane];
        const float v0 = b2f((unsigned short)(p0 & 0xFFFF));
        acc.x += v0 * b2f(s0.x); acc.y += v0 * b2f(s0.y);
        acc.z += v0 * b2f(s0.z); acc.w += v0 * b2f(s0.w);
    }

    acc.x = fmaxf(acc.x, 0.f);
    acc.y = fmaxf(acc.y, 0.f);
    acc.z = fmaxf(acc.z, 0.f);
    acc.w = fmaxf(acc.w, 0.f);
    out[(size_t)row * 64 + lane] = acc;
}

extern "C" void kernel_launch(void* const* d_in, const int* in_sizes, int n_in,
                              void* d_out, int out_size, void* d_ws, size_t ws_size,
                              hipStream_t stream) {
    const float* features  = (const float*)d_in[0];   // [50000, 512]
    const float* weight    = (const float*)d_in[1];   // [512, 256]
    const float* edge_vals = (const float*)d_in[2];   // [1.6M]
    const int*   edge_rows = (const int*)d_in[3];
    const int*   edge_cols = (const int*)d_in[4];
    float* out = (float*)d_out;                       // [50000, 256]

    // workspace layout (8B-aligned chunks first)
    unsigned short* support_bf = (unsigned short*)d_ws;                 // 25.6 MB
    int2*  binned    = (int2*)(support_bf + (size_t)N_NODES * OUT_F);   // 12.8 MB
    unsigned int* ecv = (unsigned int*)(binned + N_EDGES);              // 6.4 MB
    int*   excl      = (int*)(ecv + N_EDGES);                           // 50000
    int*   binCounts = excl + N_NODES;                                  // 512
    int*   binStart  = binCounts + 512;                                 // 512
    int*   relCur    = binStart + 512;                                  // 512
    short* Wt        = (short*)(relCur + 512);                          // 131072 bf16

    // 1) weight transpose + bf16 convert
    wt_kernel<<<(IN_F * OUT_F + 255) / 256, 256, 0, stream>>>(weight, Wt);

    // 2) MFMA GEMM: support(bf16) = features @ weight (BM=128, 8 waves)
    gemm_mfma_kernel<<<(N_NODES + 127) / 128, 512, 0, stream>>>(features, Wt, support_bf);

    // 3) two-pass edge sort (consolidated: no scanA)
    zero_bins_kernel<<<2, 256, 0, stream>>>(binCounts, relCur);
    histA_kernel<<<256, 256, 0, stream>>>(edge_rows, binCounts);
    fillA_kernel<<<NBATCHES, 256, 0, stream>>>(edge_rows, edge_cols, edge_vals,
                                               binCounts, relCur, binStart, binned);
    sortB_kernel<<<NBINS, 512, 0, stream>>>(binned, binStart, binCounts, excl, ecv);

    // 4) gather + fused ReLU (one wave per row, no atomics)
    gather_kernel<<<(N_NODES + 3) / 4, 256, 0, stream>>>(
        (const ushort4*)support_bf, excl, ecv, (float4*)out);
}

// Round 12
// 327.829 us; speedup vs baseline: 1.8057x; 1.0775x over previous
//
#include <hip/hip_runtime.h>

#define N_NODES 50000
#define N_EDGES 1600000
#define IN_F    512
#define OUT_F   256

// two-pass sort params: fine buckets of 128 rows
#define BROWS   128
#define NBINS   ((N_NODES + BROWS - 1) / BROWS)    // 391
#define BATCH   4096
#define NBATCHES ((N_EDGES + BATCH - 1) / BATCH)   // 391
#define EPT     (BATCH / 256)                      // 16 edges per thread

typedef __attribute__((ext_vector_type(8))) short bf16x8;
typedef __attribute__((ext_vector_type(4))) float f32x4;
typedef unsigned long long ull;

__device__ __forceinline__ short bf16rne(float f) {
    unsigned u = __builtin_bit_cast(unsigned, f);
    u += 0x7fffu + ((u >> 16) & 1u);          // round-to-nearest-even
    return (short)(u >> 16);
}

__device__ __forceinline__ float b2f(unsigned short h) {
    unsigned u = (unsigned)h << 16;
    return __builtin_bit_cast(float, u);
}

// ---------------------------------------------------------------------------
// Kernel 0: Wt[n][k] = bf16(W[k][n])  — transpose + convert weight (512x256)
// ---------------------------------------------------------------------------
__global__ __launch_bounds__(256) void wt_kernel(const float* __restrict__ W,
                                                 short* __restrict__ Wt) {
    int idx = blockIdx.x * 256 + threadIdx.x;
    if (idx < IN_F * OUT_F) {
        int n = idx >> 9;          // /512
        int k = idx & 511;
        Wt[idx] = bf16rne(W[(size_t)k * OUT_F + n]);
    }
}

// ---------------------------------------------------------------------------
// Kernel 1: support(bf16) = features @ weight via bf16 MFMA.
// BM=128, BN=256 (full N), BK=32. 8 waves (512 thr): wave-tile 64x64.
// (R9 version, bf16 epilogue — fp8 epilogue failed absmax in R10.)
// ---------------------------------------------------------------------------
#define ASTRIDE 40
#define BSTRIDE 40

__global__ __launch_bounds__(512) void gemm_mfma_kernel(const float* __restrict__ A,
                                                        const short* __restrict__ Wt,
                                                        unsigned short* __restrict__ Cb) {
    __shared__ short As[128 * ASTRIDE];
    __shared__ short Bs[256 * BSTRIDE];

    const int tid  = threadIdx.x;
    const int wave = tid >> 6;
    const int lane = tid & 63;
    const int m0   = blockIdx.x * 128;
    const int wrow = (wave >> 2) * 64;       // 0 or 64
    const int wcol = (wave & 3) * 64;        // 0/64/128/192

    const int quad = lane >> 4;
    const int l16  = lane & 15;

    const int ar = tid >> 2;                 // 0..127 (A row within tile)
    const int aq = tid & 3;                  // 0..3   (8-wide k chunk)

    const int bn = tid >> 1;                 // 0..255 (B row = out col)
    const int bh = tid & 1;                  // 0..1   (16-wide k half)

    f32x4 zero4 = {0.f, 0.f, 0.f, 0.f};
    f32x4 acc[4][4];
#pragma unroll
    for (int i = 0; i < 4; ++i)
#pragma unroll
        for (int j = 0; j < 4; ++j) acc[i][j] = zero4;

    for (int k0 = 0; k0 < IN_F; k0 += 32) {
        {
            const int gm = m0 + ar;
            float4 v0 = make_float4(0.f, 0.f, 0.f, 0.f);
            float4 v1 = v0;
            if (gm < N_NODES) {
                const float* p = A + (size_t)gm * IN_F + k0 + aq * 8;
                v0 = *(const float4*)p;
                v1 = *(const float4*)(p + 4);
            }
            bf16x8 b;
            b[0] = bf16rne(v0.x); b[1] = bf16rne(v0.y);
            b[2] = bf16rne(v0.z); b[3] = bf16rne(v0.w);
            b[4] = bf16rne(v1.x); b[5] = bf16rne(v1.y);
            b[6] = bf16rne(v1.z); b[7] = bf16rne(v1.w);
            *(bf16x8*)&As[ar * ASTRIDE + aq * 8] = b;
        }
        {
            const short* src = Wt + (size_t)bn * IN_F + k0 + bh * 16;
            bf16x8 w0 = *(const bf16x8*)(src + 0);
            bf16x8 w1 = *(const bf16x8*)(src + 8);
            short* dst = &Bs[bn * BSTRIDE + bh * 16];
            *(bf16x8*)(dst + 0) = w0;
            *(bf16x8*)(dst + 8) = w1;
        }
        __syncthreads();

        bf16x8 af[4], bf[4];
#pragma unroll
        for (int mt = 0; mt < 4; ++mt)
            af[mt] = *(const bf16x8*)&As[(wrow + mt * 16 + l16) * ASTRIDE + quad * 8];
#pragma unroll
        for (int nt = 0; nt < 4; ++nt)
            bf[nt] = *(const bf16x8*)&Bs[(wcol + nt * 16 + l16) * BSTRIDE + quad * 8];

#pragma unroll
        for (int mt = 0; mt < 4; ++mt)
#pragma unroll
            for (int nt = 0; nt < 4; ++nt)
                acc[mt][nt] = __builtin_amdgcn_mfma_f32_16x16x32_bf16(
                    af[mt], bf[nt], acc[mt][nt], 0, 0, 0);
        __syncthreads();
    }

#pragma unroll
    for (int mt = 0; mt < 4; ++mt) {
        const int rbase = m0 + wrow + mt * 16 + quad * 4;
#pragma unroll
        for (int i = 0; i < 4; ++i) {
            const int row = rbase + i;
            if (row < N_NODES) {
#pragma unroll
                for (int nt = 0; nt < 4; ++nt)
                    Cb[(size_t)row * OUT_F + wcol + nt * 16 + l16] =
                        (unsigned short)bf16rne(acc[mt][nt][i]);
            }
        }
    }
}

// ---------------------------------------------------------------------------
// Quantize: per-row symmetric int8 (biased uint8) + fp32 scale.
// One wave per row: wave-max of |support_bf16|, scale = max/127,
// q = rint(v*127/max)+128 packed 4/lane. Error ulp = rowmax/127 (~4.8x
// smaller rms than e4m3's |s|/8 — the R10 failure mode).
// Runs AFTER sortB so the int8 table aliases the then-dead `binned` buffer.
// ---------------------------------------------------------------------------
__global__ __launch_bounds__(256) void quant_kernel(const ushort4* __restrict__ sup16,
                                                    unsigned int* __restrict__ sup8,
                                                    float* __restrict__ scales) {
    const int tid  = threadIdx.x;
    const int row  = blockIdx.x * 4 + (tid >> 6);
    const int lane = tid & 63;
    if (row >= N_NODES) return;

    const ushort4 v = sup16[(size_t)row * 64 + lane];
    const float a0 = b2f(v.x), a1 = b2f(v.y), a2 = b2f(v.z), a3 = b2f(v.w);
    float m = fmaxf(fmaxf(fabsf(a0), fabsf(a1)), fmaxf(fabsf(a2), fabsf(a3)));
#pragma unroll
    for (int off = 32; off >= 1; off >>= 1)
        m = fmaxf(m, __shfl_xor(m, off, 64));

    const float inv = (m > 0.f) ? 127.f / m : 0.f;
    const int q0 = (int)rintf(a0 * inv) + 128;
    const int q1 = (int)rintf(a1 * inv) + 128;
    const int q2 = (int)rintf(a2 * inv) + 128;
    const int q3 = (int)rintf(a3 * inv) + 128;
    sup8[(size_t)row * 64 + lane] =
        (unsigned)q0 | ((unsigned)q1 << 8) | ((unsigned)q2 << 16) | ((unsigned)q3 << 24);
    if (lane == 0) scales[row] = m * (1.f / 127.f);
}

// ---------------------------------------------------------------------------
// Two-pass edge sort (391 buckets x 128 rows), consolidated (R9, unchanged).
// ---------------------------------------------------------------------------
__global__ __launch_bounds__(256) void zero_bins_kernel(int* __restrict__ binCounts,
                                                        int* __restrict__ relCur) {
    int i = blockIdx.x * 256 + threadIdx.x;
    if (i < NBINS) { binCounts[i] = 0; relCur[i] = 0; }
}

__global__ __launch_bounds__(256) void histA_kernel(const int* __restrict__ rows,
                                                    int* __restrict__ binCounts) {
    __shared__ int lh[NBINS];
    const int tid = threadIdx.x;
    for (int i = tid; i < NBINS; i += 256) lh[i] = 0;
    __syncthreads();
    for (int i = blockIdx.x * 256 + tid; i < N_EDGES; i += gridDim.x * 256)
        atomicAdd(&lh[rows[i] >> 7], 1);
    __syncthreads();
    for (int i = tid; i < NBINS; i += 256)
        if (lh[i]) atomicAdd(&binCounts[i], lh[i]);
}

__global__ __launch_bounds__(256) void fillA_kernel(const int* __restrict__ rows,
                                                    const int* __restrict__ cols,
                                                    const float* __restrict__ vals,
                                                    const int* __restrict__ binCounts,
                                                    int* __restrict__ relCur,
                                                    int* __restrict__ binStart,
                                                    int2* __restrict__ binned) {
    __shared__ int lhist[NBINS];
    __shared__ int lexcl[NBINS];
    __shared__ int gbase[NBINS];
    __shared__ ull stmp2[256];
    __shared__ int2 lstage[BATCH];
    __shared__ unsigned short sbucket[BATCH];

    const int tid   = threadIdx.x;
    const int start = blockIdx.x * BATCH;
    const int count = min(BATCH, N_EDGES - start);

    for (int i = tid; i < NBINS; i += 256) lhist[i] = 0;
    __syncthreads();

    int myrow[EPT], myrank[EPT];
#pragma unroll
    for (int j = 0; j < EPT; ++j) {
        const int s = j * 256 + tid;
        if (s < count) {
            const int r = rows[start + s];
            myrow[j]  = r;
            myrank[j] = atomicAdd(&lhist[r >> 7], 1);
        }
    }
    __syncthreads();

    // dual pair-scan: high 32b = binCounts prefix (global), low 32b = lhist
    // prefix (local). Low total <= BATCH so no carry into high field.
    {
        const int i0 = 2 * tid, i1 = 2 * tid + 1;
        const int h0 = (i0 < NBINS) ? lhist[i0] : 0;
        const int h1 = (i1 < NBINS) ? lhist[i1] : 0;
        const int c0 = (i0 < NBINS) ? binCounts[i0] : 0;
        const int c1 = (i1 < NBINS) ? binCounts[i1] : 0;
        const ull pair = ((ull)(unsigned)(c0 + c1) << 32) | (unsigned)(h0 + h1);
        stmp2[tid] = pair;
        for (int off = 1; off < 256; off <<= 1) {
            __syncthreads();
            ull t = (tid >= off) ? stmp2[tid - off] : 0ull;
            __syncthreads();
            stmp2[tid] += t;
        }
        __syncthreads();
        const ull pex  = stmp2[tid] - pair;
        const int lex0 = (int)(pex & 0xffffffffull);
        const int bst0 = (int)(pex >> 32);
        if (i0 < NBINS) {
            lexcl[i0] = lex0;
            gbase[i0] = bst0 + (h0 ? atomicAdd(&relCur[i0], h0) : 0);
            if (blockIdx.x == 0) binStart[i0] = bst0;
        }
        if (i1 < NBINS) {
            lexcl[i1] = lex0 + h0;
            gbase[i1] = (bst0 + c0) + (h1 ? atomicAdd(&relCur[i1], h1) : 0);
            if (blockIdx.x == 0) binStart[i1] = bst0 + c0;
        }
    }
    __syncthreads();

    // stage into LDS ordered by bucket
#pragma unroll
    for (int j = 0; j < EPT; ++j) {
        const int s = j * 256 + tid;
        if (s < count) {
            const int r   = myrow[j];
            const int b   = r >> 7;
            const int pos = lexcl[b] + myrank[j];
            lstage[pos]  = make_int2(((r & 127) << 16) | cols[start + s],
                                     __float_as_int(vals[start + s]));
            sbucket[pos] = (unsigned short)b;
        }
    }
    __syncthreads();

    // write out: bucket runs contiguous
#pragma unroll
    for (int j = 0; j < EPT; ++j) {
        const int s = j * 256 + tid;
        if (s < count) {
            const int b = sbucket[s];
            binned[gbase[b] + (s - lexcl[b])] = lstage[s];
        }
    }
}

__global__ __launch_bounds__(512) void sortB_kernel(const int2* __restrict__ binned,
                                                    const int* __restrict__ binStart,
                                                    const int* __restrict__ binCounts,
                                                    int* __restrict__ excl,
                                                    unsigned int* __restrict__ ecv) {
    __shared__ int lhist[BROWS];
    __shared__ int lcur[BROWS];

    const int tid  = threadIdx.x;
    const int b    = blockIdx.x;
    const int base = binStart[b];
    const int cnt  = binCounts[b];

    if (tid < BROWS) lhist[tid] = 0;
    __syncthreads();

    for (int i = tid; i < cnt; i += 512)
        atomicAdd(&lhist[binned[base + i].x >> 16], 1);
    __syncthreads();

    // scan 128 with first 128 threads (Hillis-Steele in lcur as temp)
    if (tid < BROWS) lcur[tid] = lhist[tid];
    for (int off = 1; off < BROWS; off <<= 1) {
        __syncthreads();
        int t = (tid >= off && tid < BROWS) ? lcur[tid - off] : 0;
        __syncthreads();
        if (tid < BROWS) lcur[tid] += t;
    }
    __syncthreads();
    if (tid < BROWS) {
        const int pexcl = lcur[tid] - lhist[tid];
        const int row   = b * BROWS + tid;
        lcur[tid] = pexcl;
        if (row < N_NODES) excl[row] = base + pexcl;
    }
    __syncthreads();

    for (int i = tid; i < cnt; i += 512) {
        const int2 e  = binned[base + i];
        const int rl  = e.x >> 16;
        const int col = e.x & 0xFFFF;
        const int rank = atomicAdd(&lcur[rl], 1);
        ecv[base + rank] = ((unsigned int)col << 16) |
                           (unsigned short)bf16rne(__int_as_float(e.y));
    }
}

// ---------------------------------------------------------------------------
// Gather, int8 support: row = 256B = 2 x 128B lines/edge (vs 4 at bf16).
// One wave per row; lane owns 4 features (1 dword of biased-uint8/edge);
// decode (float)(byte) folds to v_cvt_f32_ubyte; bias corrected once per
// output via csum: acc_f = sum v'*u_f - 128*sum v', v' = val*scale[col]
// (scale load is wave-uniform broadcast, L1-resident). Fused ReLU.
// ---------------------------------------------------------------------------
__global__ __launch_bounds__(256) void gather_kernel(const unsigned int* __restrict__ support,
                                                     const float* __restrict__ scales,
                                                     const int* __restrict__ excl,
                                                     const unsigned int* __restrict__ ecv,
                                                     float4* __restrict__ out) {
    const int tid  = threadIdx.x;
    const int row  = blockIdx.x * 4 + (tid >> 6);
    const int lane = tid & 63;
    if (row >= N_NODES) return;

    const int start = excl[row];
    const int end   = (row + 1 < N_NODES) ? excl[row + 1] : N_EDGES;

    float4 acc = make_float4(0.f, 0.f, 0.f, 0.f);
    float csum = 0.f;
    int e = start;
    const int end4 = start + ((end - start) & ~3);
    for (; e < end4; e += 4) {
        const unsigned int p0 = ecv[e];
        const unsigned int p1 = ecv[e + 1];
        const unsigned int p2 = ecv[e + 2];
        const unsigned int p3 = ecv[e + 3];
        const int c0 = p0 >> 16, c1 = p1 >> 16, c2 = p2 >> 16, c3 = p3 >> 16;
        const unsigned int u0 = support[(size_t)c0 * 64 + lane];
        const unsigned int u1 = support[(size_t)c1 * 64 + lane];
        const unsigned int u2 = support[(size_t)c2 * 64 + lane];
        const unsigned int u3 = support[(size_t)c3 * 64 + lane];
        const float v0 = b2f((unsigned short)(p0 & 0xFFFF)) * scales[c0];
        const float v1 = b2f((unsigned short)(p1 & 0xFFFF)) * scales[c1];
        const float v2 = b2f((unsigned short)(p2 & 0xFFFF)) * scales[c2];
        const float v3 = b2f((unsigned short)(p3 & 0xFFFF)) * scales[c3];
        csum += v0 + v1 + v2 + v3;
        acc.x += v0 * (float)(u0 & 0xff)         + v1 * (float)(u1 & 0xff)
               + v2 * (float)(u2 & 0xff)         + v3 * (float)(u3 & 0xff);
        acc.y += v0 * (float)((u0 >> 8) & 0xff)  + v1 * (float)((u1 >> 8) & 0xff)
               + v2 * (float)((u2 >> 8) & 0xff)  + v3 * (float)((u3 >> 8) & 0xff);
        acc.z += v0 * (float)((u0 >> 16) & 0xff) + v1 * (float)((u1 >> 16) & 0xff)
               + v2 * (float)((u2 >> 16) & 0xff) + v3 * (float)((u3 >> 16) & 0xff);
        acc.w += v0 * (float)(u0 >> 24)          + v1 * (float)(u1 >> 24)
               + v2 * (float)(u2 >> 24)          + v3 * (float)(u3 >> 24);
    }
    for (; e < end; ++e) {
        const unsigned int p0 = ecv[e];
        const int c0 = p0 >> 16;
        const unsigned int u0 = support[(size_t)c0 * 64 + lane];
        const float v0 = b2f((unsigned short)(p0 & 0xFFFF)) * scales[c0];
        csum += v0;
        acc.x += v0 * (float)(u0 & 0xff);
        acc.y += v0 * (float)((u0 >> 8) & 0xff);
        acc.z += v0 * (float)((u0 >> 16) & 0xff);
        acc.w += v0 * (float)(u0 >> 24);
    }

    const float bias = 128.f * csum;
    acc.x = fmaxf(acc.x - bias, 0.f);
    acc.y = fmaxf(acc.y - bias, 0.f);
    acc.z = fmaxf(acc.z - bias, 0.f);
    acc.w = fmaxf(acc.w - bias, 0.f);
    out[(size_t)row * 64 + lane] = acc;
}

extern "C" void kernel_launch(void* const* d_in, const int* in_sizes, int n_in,
                              void* d_out, int out_size, void* d_ws, size_t ws_size,
                              hipStream_t stream) {
    const float* features  = (const float*)d_in[0];   // [50000, 512]
    const float* weight    = (const float*)d_in[1];   // [512, 256]
    const float* edge_vals = (const float*)d_in[2];   // [1.6M]
    const int*   edge_rows = (const int*)d_in[3];
    const int*   edge_cols = (const int*)d_in[4];
    float* out = (float*)d_out;                       // [50000, 256]

    // workspace layout (8B-aligned chunks first)
    unsigned short* support_bf = (unsigned short*)d_ws;                 // 25.6 MB
    int2*  binned    = (int2*)(support_bf + (size_t)N_NODES * OUT_F);   // 12.8 MB
    unsigned int* ecv = (unsigned int*)(binned + N_EDGES);              // 6.4 MB
    int*   excl      = (int*)(ecv + N_EDGES);                           // 50000
    int*   binCounts = excl + N_NODES;                                  // 512
    int*   binStart  = binCounts + 512;                                 // 512
    int*   relCur    = binStart + 512;                                  // 512
    float* scales    = (float*)(relCur + 512);                          // 50000 f32
    short* Wt        = (short*)(scales + N_NODES);                      // 131072 bf16
    // int8 support table aliases `binned` (dead after sortB; both 12.8 MB)
    unsigned int* support_i8 = (unsigned int*)binned;

    // 1) weight transpose + bf16 convert
    wt_kernel<<<(IN_F * OUT_F + 255) / 256, 256, 0, stream>>>(weight, Wt);

    // 2) MFMA GEMM: support(bf16) = features @ weight (BM=128, 8 waves)
    gemm_mfma_kernel<<<(N_NODES + 127) / 128, 512, 0, stream>>>(features, Wt, support_bf);

    // 3) two-pass edge sort (consolidated: no scanA)
    zero_bins_kernel<<<2, 256, 0, stream>>>(binCounts, relCur);
    histA_kernel<<<256, 256, 0, stream>>>(edge_rows, binCounts);
    fillA_kernel<<<NBATCHES, 256, 0, stream>>>(edge_rows, edge_cols, edge_vals,
                                               binCounts, relCur, binStart, binned);
    sortB_kernel<<<NBINS, 512, 0, stream>>>(binned, binStart, binCounts, excl, ecv);

    // 4) quantize support bf16 -> per-row int8 (+ scales); binned now dead
    quant_kernel<<<(N_NODES + 3) / 4, 256, 0, stream>>>(
        (const ushort4*)support_bf, support_i8, scales);

    // 5) gather + fused ReLU (one wave per row, int8 support, no atomics)
    gather_kernel<<<(N_NODES + 3) / 4, 256, 0, stream>>>(
        support_i8, scales, excl, ecv, (float4*)out);
}

// Round 13
// 322.797 us; speedup vs baseline: 1.8338x; 1.0156x over previous
//
#include <hip/hip_runtime.h>

#define N_NODES 50000
#define N_EDGES 1600000
#define IN_F    512
#define OUT_F   256

// two-pass sort params: fine buckets of 128 rows
#define BROWS   128
#define NBINS   ((N_NODES + BROWS - 1) / BROWS)    // 391
#define BATCH   4096
#define NBATCHES ((N_EDGES + BATCH - 1) / BATCH)   // 391
#define EPT     (BATCH / 256)                      // 16 edges per thread

typedef __attribute__((ext_vector_type(8))) short bf16x8;
typedef __attribute__((ext_vector_type(4))) float f32x4;
typedef unsigned long long ull;

__device__ __forceinline__ short bf16rne(float f) {
    unsigned u = __builtin_bit_cast(unsigned, f);
    u += 0x7fffu + ((u >> 16) & 1u);          // round-to-nearest-even
    return (short)(u >> 16);
}

__device__ __forceinline__ float b2f(unsigned short h) {
    unsigned u = (unsigned)h << 16;
    return __builtin_bit_cast(float, u);
}

// ---------------------------------------------------------------------------
// Kernel 0: Wt[n][k] = bf16(W[k][n])  — transpose + convert weight (512x256)
// ---------------------------------------------------------------------------
__global__ __launch_bounds__(256) void wt_kernel(const float* __restrict__ W,
                                                 short* __restrict__ Wt) {
    int idx = blockIdx.x * 256 + threadIdx.x;
    if (idx < IN_F * OUT_F) {
        int n = idx >> 9;          // /512
        int k = idx & 511;
        Wt[idx] = bf16rne(W[(size_t)k * OUT_F + n]);
    }
}

// ---------------------------------------------------------------------------
// Kernel 1: FUSED GEMM + per-row int8 quantization.
// support = features @ weight via bf16 MFMA (BM=128, BN=256 full row, BK=32,
// 8 waves). Epilogue: row-max via shfl(l16) + LDS cross-wave(4) reduce, then
// quantize f32 acc -> biased uint8 (q = rint(v*127/max)+128), write bytes +
// per-row scale. Kills the separate quant kernel and the 25.6MB bf16 table.
// ---------------------------------------------------------------------------
#define ASTRIDE 40
#define BSTRIDE 40

__global__ __launch_bounds__(512) void gemm_mfma_kernel(const float* __restrict__ A,
                                                        const short* __restrict__ Wt,
                                                        unsigned char* __restrict__ Cb8,
                                                        float* __restrict__ scales) {
    __shared__ short As[128 * ASTRIDE];
    __shared__ short Bs[256 * BSTRIDE];
    __shared__ float redmax[128][5];         // [row_local][wave-col], +pad

    const int tid  = threadIdx.x;
    const int wave = tid >> 6;
    const int lane = tid & 63;
    const int m0   = blockIdx.x * 128;
    const int wrow = (wave >> 2) * 64;       // 0 or 64
    const int wcol = (wave & 3) * 64;        // 0/64/128/192

    const int quad = lane >> 4;
    const int l16  = lane & 15;

    const int ar = tid >> 2;                 // 0..127 (A row within tile)
    const int aq = tid & 3;                  // 0..3   (8-wide k chunk)

    const int bn = tid >> 1;                 // 0..255 (B row = out col)
    const int bh = tid & 1;                  // 0..1   (16-wide k half)

    f32x4 zero4 = {0.f, 0.f, 0.f, 0.f};
    f32x4 acc[4][4];
#pragma unroll
    for (int i = 0; i < 4; ++i)
#pragma unroll
        for (int j = 0; j < 4; ++j) acc[i][j] = zero4;

    for (int k0 = 0; k0 < IN_F; k0 += 32) {
        {
            const int gm = m0 + ar;
            float4 v0 = make_float4(0.f, 0.f, 0.f, 0.f);
            float4 v1 = v0;
            if (gm < N_NODES) {
                const float* p = A + (size_t)gm * IN_F + k0 + aq * 8;
                v0 = *(const float4*)p;
                v1 = *(const float4*)(p + 4);
            }
            bf16x8 b;
            b[0] = bf16rne(v0.x); b[1] = bf16rne(v0.y);
            b[2] = bf16rne(v0.z); b[3] = bf16rne(v0.w);
            b[4] = bf16rne(v1.x); b[5] = bf16rne(v1.y);
            b[6] = bf16rne(v1.z); b[7] = bf16rne(v1.w);
            *(bf16x8*)&As[ar * ASTRIDE + aq * 8] = b;
        }
        {
            const short* src = Wt + (size_t)bn * IN_F + k0 + bh * 16;
            bf16x8 w0 = *(const bf16x8*)(src + 0);
            bf16x8 w1 = *(const bf16x8*)(src + 8);
            short* dst = &Bs[bn * BSTRIDE + bh * 16];
            *(bf16x8*)(dst + 0) = w0;
            *(bf16x8*)(dst + 8) = w1;
        }
        __syncthreads();

        bf16x8 af[4], bf[4];
#pragma unroll
        for (int mt = 0; mt < 4; ++mt)
            af[mt] = *(const bf16x8*)&As[(wrow + mt * 16 + l16) * ASTRIDE + quad * 8];
#pragma unroll
        for (int nt = 0; nt < 4; ++nt)
            bf[nt] = *(const bf16x8*)&Bs[(wcol + nt * 16 + l16) * BSTRIDE + quad * 8];

#pragma unroll
        for (int mt = 0; mt < 4; ++mt)
#pragma unroll
            for (int nt = 0; nt < 4; ++nt)
                acc[mt][nt] = __builtin_amdgcn_mfma_f32_16x16x32_bf16(
                    af[mt], bf[nt], acc[mt][nt], 0, 0, 0);
        __syncthreads();
    }

    // ---- fused per-row int8 quantization epilogue ----
    // per-lane |max| over this wave's 4 col-tiles, for each of 16 owned rows
    float pm[4][4];                          // [mt][i]
#pragma unroll
    for (int mt = 0; mt < 4; ++mt)
#pragma unroll
        for (int i = 0; i < 4; ++i) {
            float m = fabsf(acc[mt][0][i]);
            m = fmaxf(m, fabsf(acc[mt][1][i]));
            m = fmaxf(m, fabsf(acc[mt][2][i]));
            m = fmaxf(m, fabsf(acc[mt][3][i]));
            pm[mt][i] = m;
        }
    // reduce across the 16 l16-lanes (same rows, different cols); xor of
    // bits 0..3 stays inside the quad group
#pragma unroll
    for (int off = 1; off < 16; off <<= 1)
#pragma unroll
        for (int mt = 0; mt < 4; ++mt)
#pragma unroll
            for (int i = 0; i < 4; ++i)
                pm[mt][i] = fmaxf(pm[mt][i], __shfl_xor(pm[mt][i], off, 64));

    if (l16 == 0) {
#pragma unroll
        for (int mt = 0; mt < 4; ++mt)
#pragma unroll
            for (int i = 0; i < 4; ++i)
                redmax[wrow + mt * 16 + quad * 4 + i][wave & 3] = pm[mt][i];
    }
    __syncthreads();

#pragma unroll
    for (int mt = 0; mt < 4; ++mt) {
#pragma unroll
        for (int i = 0; i < 4; ++i) {
            const int rl  = wrow + mt * 16 + quad * 4 + i;
            const int row = m0 + rl;
            if (row < N_NODES) {
                const float m = fmaxf(fmaxf(redmax[rl][0], redmax[rl][1]),
                                      fmaxf(redmax[rl][2], redmax[rl][3]));
                const float inv = (m > 0.f) ? 127.f / m : 0.f;
#pragma unroll
                for (int nt = 0; nt < 4; ++nt) {
                    const int q = (int)rintf(acc[mt][nt][i] * inv) + 128;
                    Cb8[(size_t)row * OUT_F + wcol + nt * 16 + l16] = (unsigned char)q;
                }
                if ((wave & 3) == 0 && l16 == 0)
                    scales[row] = m * (1.f / 127.f);
            }
        }
    }
}

// ---------------------------------------------------------------------------
// Two-pass edge sort (391 buckets x 128 rows), consolidated (R9).
// sortB now FOLDS the support row-scale into the edge value:
//   ecv = col<<16 | bf16(val * scales[col])
// so the gather needs no per-edge scale load (R12 counters: those 1.6M
// scalar loads were +50% L2 request traffic on the gather critical path).
// ---------------------------------------------------------------------------
__global__ __launch_bounds__(256) void zero_bins_kernel(int* __restrict__ binCounts,
                                                        int* __restrict__ relCur) {
    int i = blockIdx.x * 256 + threadIdx.x;
    if (i < NBINS) { binCounts[i] = 0; relCur[i] = 0; }
}

__global__ __launch_bounds__(256) void histA_kernel(const int* __restrict__ rows,
                                                    int* __restrict__ binCounts) {
    __shared__ int lh[NBINS];
    const int tid = threadIdx.x;
    for (int i = tid; i < NBINS; i += 256) lh[i] = 0;
    __syncthreads();
    for (int i = blockIdx.x * 256 + tid; i < N_EDGES; i += gridDim.x * 256)
        atomicAdd(&lh[rows[i] >> 7], 1);
    __syncthreads();
    for (int i = tid; i < NBINS; i += 256)
        if (lh[i]) atomicAdd(&binCounts[i], lh[i]);
}

__global__ __launch_bounds__(256) void fillA_kernel(const int* __restrict__ rows,
                                                    const int* __restrict__ cols,
                                                    const float* __restrict__ vals,
                                                    const int* __restrict__ binCounts,
                                                    int* __restrict__ relCur,
                                                    int* __restrict__ binStart,
                                                    int2* __restrict__ binned) {
    __shared__ int lhist[NBINS];
    __shared__ int lexcl[NBINS];
    __shared__ int gbase[NBINS];
    __shared__ ull stmp2[256];
    __shared__ int2 lstage[BATCH];
    __shared__ unsigned short sbucket[BATCH];

    const int tid   = threadIdx.x;
    const int start = blockIdx.x * BATCH;
    const int count = min(BATCH, N_EDGES - start);

    for (int i = tid; i < NBINS; i += 256) lhist[i] = 0;
    __syncthreads();

    int myrow[EPT], myrank[EPT];
#pragma unroll
    for (int j = 0; j < EPT; ++j) {
        const int s = j * 256 + tid;
        if (s < count) {
            const int r = rows[start + s];
            myrow[j]  = r;
            myrank[j] = atomicAdd(&lhist[r >> 7], 1);
        }
    }
    __syncthreads();

    // dual pair-scan: high 32b = binCounts prefix (global), low 32b = lhist
    // prefix (local). Low total <= BATCH so no carry into high field.
    {
        const int i0 = 2 * tid, i1 = 2 * tid + 1;
        const int h0 = (i0 < NBINS) ? lhist[i0] : 0;
        const int h1 = (i1 < NBINS) ? lhist[i1] : 0;
        const int c0 = (i0 < NBINS) ? binCounts[i0] : 0;
        const int c1 = (i1 < NBINS) ? binCounts[i1] : 0;
        const ull pair = ((ull)(unsigned)(c0 + c1) << 32) | (unsigned)(h0 + h1);
        stmp2[tid] = pair;
        for (int off = 1; off < 256; off <<= 1) {
            __syncthreads();
            ull t = (tid >= off) ? stmp2[tid - off] : 0ull;
            __syncthreads();
            stmp2[tid] += t;
        }
        __syncthreads();
        const ull pex  = stmp2[tid] - pair;
        const int lex0 = (int)(pex & 0xffffffffull);
        const int bst0 = (int)(pex >> 32);
        if (i0 < NBINS) {
            lexcl[i0] = lex0;
            gbase[i0] = bst0 + (h0 ? atomicAdd(&relCur[i0], h0) : 0);
            if (blockIdx.x == 0) binStart[i0] = bst0;
        }
        if (i1 < NBINS) {
            lexcl[i1] = lex0 + h0;
            gbase[i1] = (bst0 + c0) + (h1 ? atomicAdd(&relCur[i1], h1) : 0);
            if (blockIdx.x == 0) binStart[i1] = bst0 + c0;
        }
    }
    __syncthreads();

    // stage into LDS ordered by bucket
#pragma unroll
    for (int j = 0; j < EPT; ++j) {
        const int s = j * 256 + tid;
        if (s < count) {
            const int r   = myrow[j];
            const int b   = r >> 7;
            const int pos = lexcl[b] + myrank[j];
            lstage[pos]  = make_int2(((r & 127) << 16) | cols[start + s],
                                     __float_as_int(vals[start + s]));
            sbucket[pos] = (unsigned short)b;
        }
    }
    __syncthreads();

    // write out: bucket runs contiguous
#pragma unroll
    for (int j = 0; j < EPT; ++j) {
        const int s = j * 256 + tid;
        if (s < count) {
            const int b = sbucket[s];
            binned[gbase[b] + (s - lexcl[b])] = lstage[s];
        }
    }
}

__global__ __launch_bounds__(512) void sortB_kernel(const int2* __restrict__ binned,
                                                    const int* __restrict__ binStart,
                                                    const int* __restrict__ binCounts,
                                                    const float* __restrict__ scales,
                                                    int* __restrict__ excl,
                                                    unsigned int* __restrict__ ecv) {
    __shared__ int lhist[BROWS];
    __shared__ int lcur[BROWS];

    const int tid  = threadIdx.x;
    const int b    = blockIdx.x;
    const int base = binStart[b];
    const int cnt  = binCounts[b];

    if (tid < BROWS) lhist[tid] = 0;
    __syncthreads();

    for (int i = tid; i < cnt; i += 512)
        atomicAdd(&lhist[binned[base + i].x >> 16], 1);
    __syncthreads();

    // scan 128 with first 128 threads (Hillis-Steele in lcur as temp)
    if (tid < BROWS) lcur[tid] = lhist[tid];
    for (int off = 1; off < BROWS; off <<= 1) {
        __syncthreads();
        int t = (tid >= off && tid < BROWS) ? lcur[tid - off] : 0;
        __syncthreads();
        if (tid < BROWS) lcur[tid] += t;
    }
    __syncthreads();
    if (tid < BROWS) {
        const int pexcl = lcur[tid] - lhist[tid];
        const int row   = b * BROWS + tid;
        lcur[tid] = pexcl;
        if (row < N_NODES) excl[row] = base + pexcl;
    }
    __syncthreads();

    for (int i = tid; i < cnt; i += 512) {
        const int2 e  = binned[base + i];
        const int rl  = e.x >> 16;
        const int col = e.x & 0xFFFF;
        const int rank = atomicAdd(&lcur[rl], 1);
        const float vs = __int_as_float(e.y) * scales[col];   // fold row scale
        ecv[base + rank] = ((unsigned int)col << 16) |
                           (unsigned short)bf16rne(vs);
    }
}

// ---------------------------------------------------------------------------
// Gather, int8 support (2 x 128B lines/edge), scale pre-folded into ecv.
// One wave per row; lane owns 4 features (1 dword of biased-uint8/edge);
// bias corrected once per output: acc_f = sum v'*u - 128*sum v'. Fused ReLU.
// No per-edge scale loads (R12's +50% request overhead removed).
// ---------------------------------------------------------------------------
__global__ __launch_bounds__(256) void gather_kernel(const unsigned int* __restrict__ support,
                                                     const int* __restrict__ excl,
                                                     const unsigned int* __restrict__ ecv,
                                                     float4* __restrict__ out) {
    const int tid  = threadIdx.x;
    const int row  = blockIdx.x * 4 + (tid >> 6);
    const int lane = tid & 63;
    if (row >= N_NODES) return;

    const int start = excl[row];
    const int end   = (row + 1 < N_NODES) ? excl[row + 1] : N_EDGES;

    float4 acc = make_float4(0.f, 0.f, 0.f, 0.f);
    float csum = 0.f;
    int e = start;
    const int end4 = start + ((end - start) & ~3);
    for (; e < end4; e += 4) {
        const unsigned int p0 = ecv[e];
        const unsigned int p1 = ecv[e + 1];
        const unsigned int p2 = ecv[e + 2];
        const unsigned int p3 = ecv[e + 3];
        const unsigned int u0 = support[(size_t)(p0 >> 16) * 64 + lane];
        const unsigned int u1 = support[(size_t)(p1 >> 16) * 64 + lane];
        const unsigned int u2 = support[(size_t)(p2 >> 16) * 64 + lane];
        const unsigned int u3 = support[(size_t)(p3 >> 16) * 64 + lane];
        const float v0 = b2f((unsigned short)(p0 & 0xFFFF));
        const float v1 = b2f((unsigned short)(p1 & 0xFFFF));
        const float v2 = b2f((unsigned short)(p2 & 0xFFFF));
        const float v3 = b2f((unsigned short)(p3 & 0xFFFF));
        csum += v0 + v1 + v2 + v3;
        acc.x += v0 * (float)(u0 & 0xff)         + v1 * (float)(u1 & 0xff)
               + v2 * (float)(u2 & 0xff)         + v3 * (float)(u3 & 0xff);
        acc.y += v0 * (float)((u0 >> 8) & 0xff)  + v1 * (float)((u1 >> 8) & 0xff)
               + v2 * (float)((u2 >> 8) & 0xff)  + v3 * (float)((u3 >> 8) & 0xff);
        acc.z += v0 * (float)((u0 >> 16) & 0xff) + v1 * (float)((u1 >> 16) & 0xff)
               + v2 * (float)((u2 >> 16) & 0xff) + v3 * (float)((u3 >> 16) & 0xff);
        acc.w += v0 * (float)(u0 >> 24)          + v1 * (float)(u1 >> 24)
               + v2 * (float)(u2 >> 24)          + v3 * (float)(u3 >> 24);
    }
    for (; e < end; ++e) {
        const unsigned int p0 = ecv[e];
        const unsigned int u0 = support[(size_t)(p0 >> 16) * 64 + lane];
        const float v0 = b2f((unsigned short)(p0 & 0xFFFF));
        csum += v0;
        acc.x += v0 * (float)(u0 & 0xff);
        acc.y += v0 * (float)((u0 >> 8) & 0xff);
        acc.z += v0 * (float)((u0 >> 16) & 0xff);
        acc.w += v0 * (float)(u0 >> 24);
    }

    const float bias = 128.f * csum;
    acc.x = fmaxf(acc.x - bias, 0.f);
    acc.y = fmaxf(acc.y - bias, 0.f);
    acc.z = fmaxf(acc.z - bias, 0.f);
    acc.w = fmaxf(acc.w - bias, 0.f);
    out[(size_t)row * 64 + lane] = acc;
}

extern "C" void kernel_launch(void* const* d_in, const int* in_sizes, int n_in,
                              void* d_out, int out_size, void* d_ws, size_t ws_size,
                              hipStream_t stream) {
    const float* features  = (const float*)d_in[0];   // [50000, 512]
    const float* weight    = (const float*)d_in[1];   // [512, 256]
    const float* edge_vals = (const float*)d_in[2];   // [1.6M]
    const int*   edge_rows = (const int*)d_in[3];
    const int*   edge_cols = (const int*)d_in[4];
    float* out = (float*)d_out;                       // [50000, 256]

    // workspace layout (8B-aligned chunks first)  — total ~32.7 MB
    unsigned int* support_i8 = (unsigned int*)d_ws;                     // 12.8 MB
    int2*  binned    = (int2*)(support_i8 + (size_t)N_NODES * 64);      // 12.8 MB
    unsigned int* ecv = (unsigned int*)(binned + N_EDGES);              // 6.4 MB
    int*   excl      = (int*)(ecv + N_EDGES);                           // 50000
    int*   binCounts = excl + N_NODES;                                  // 512
    int*   binStart  = binCounts + 512;                                 // 512
    int*   relCur    = binStart + 512;                                  // 512
    float* scales    = (float*)(relCur + 512);                          // 50000 f32
    short* Wt        = (short*)(scales + N_NODES);                      // 131072 bf16

    // 1) weight transpose + bf16 convert
    wt_kernel<<<(IN_F * OUT_F + 255) / 256, 256, 0, stream>>>(weight, Wt);

    // 2) fused MFMA GEMM + per-row int8 quantization (writes sup8 + scales)
    gemm_mfma_kernel<<<(N_NODES + 127) / 128, 512, 0, stream>>>(
        features, Wt, (unsigned char*)support_i8, scales);

    // 3) two-pass edge sort; sortB folds scales[col] into the edge value
    zero_bins_kernel<<<2, 256, 0, stream>>>(binCounts, relCur);
    histA_kernel<<<256, 256, 0, stream>>>(edge_rows, binCounts);
    fillA_kernel<<<NBATCHES, 256, 0, stream>>>(edge_rows, edge_cols, edge_vals,
                                               binCounts, relCur, binStart, binned);
    sortB_kernel<<<NBINS, 512, 0, stream>>>(binned, binStart, binCounts, scales,
                                            excl, ecv);

    // 4) gather + fused ReLU (one wave per row, int8 support, no scale loads)
    gather_kernel<<<(N_NODES + 3) / 4, 256, 0, stream>>>(
        support_i8, excl, ecv, (float4*)out);
}

// Round 14
// 310.821 us; speedup vs baseline: 1.9045x; 1.0385x over previous
//
#include <hip/hip_runtime.h>

#define N_NODES 50000
#define N_EDGES 1600000
#define IN_F    512
#define OUT_F   256

// two-pass sort params: fine buckets of 128 rows
#define BROWS   128
#define NBINS   ((N_NODES + BROWS - 1) / BROWS)    // 391
#define BATCH   4096
#define NBATCHES ((N_EDGES + BATCH - 1) / BATCH)   // 391
#define EPT     (BATCH / 256)                      // 16 edges per thread

typedef __attribute__((ext_vector_type(8))) short bf16x8;
typedef __attribute__((ext_vector_type(4))) float f32x4;
typedef unsigned long long ull;

__device__ __forceinline__ short bf16rne(float f) {
    unsigned u = __builtin_bit_cast(unsigned, f);
    u += 0x7fffu + ((u >> 16) & 1u);          // round-to-nearest-even
    return (short)(u >> 16);
}

__device__ __forceinline__ float b2f(unsigned short h) {
    unsigned u = (unsigned)h << 16;
    return __builtin_bit_cast(float, u);
}

// ---------------------------------------------------------------------------
// Kernel 0: Wt[n][k] = bf16(W[k][n])  — transpose + convert weight (512x256)
// ---------------------------------------------------------------------------
__global__ __launch_bounds__(256) void wt_kernel(const float* __restrict__ W,
                                                 short* __restrict__ Wt) {
    int idx = blockIdx.x * 256 + threadIdx.x;
    if (idx < IN_F * OUT_F) {
        int n = idx >> 9;          // /512
        int k = idx & 511;
        Wt[idx] = bf16rne(W[(size_t)k * OUT_F + n]);
    }
}

// ---------------------------------------------------------------------------
// Kernel 1: FUSED GEMM + per-row int8 quantization.
// support = features @ weight via bf16 MFMA (BM=128, BN=256 full row, BK=32,
// 8 waves). Epilogue: row-max via shfl(l16) + LDS cross-wave(4) reduce, then
// quantize f32 acc -> biased uint8 (q = rint(v*127/max)+128), write bytes +
// per-row scale.
// ---------------------------------------------------------------------------
#define ASTRIDE 40
#define BSTRIDE 40

__global__ __launch_bounds__(512) void gemm_mfma_kernel(const float* __restrict__ A,
                                                        const short* __restrict__ Wt,
                                                        unsigned char* __restrict__ Cb8,
                                                        float* __restrict__ scales) {
    __shared__ short As[128 * ASTRIDE];
    __shared__ short Bs[256 * BSTRIDE];
    __shared__ float redmax[128][5];         // [row_local][wave-col], +pad

    const int tid  = threadIdx.x;
    const int wave = tid >> 6;
    const int lane = tid & 63;
    const int m0   = blockIdx.x * 128;
    const int wrow = (wave >> 2) * 64;       // 0 or 64
    const int wcol = (wave & 3) * 64;        // 0/64/128/192

    const int quad = lane >> 4;
    const int l16  = lane & 15;

    const int ar = tid >> 2;                 // 0..127 (A row within tile)
    const int aq = tid & 3;                  // 0..3   (8-wide k chunk)

    const int bn = tid >> 1;                 // 0..255 (B row = out col)
    const int bh = tid & 1;                  // 0..1   (16-wide k half)

    f32x4 zero4 = {0.f, 0.f, 0.f, 0.f};
    f32x4 acc[4][4];
#pragma unroll
    for (int i = 0; i < 4; ++i)
#pragma unroll
        for (int j = 0; j < 4; ++j) acc[i][j] = zero4;

    for (int k0 = 0; k0 < IN_F; k0 += 32) {
        {
            const int gm = m0 + ar;
            float4 v0 = make_float4(0.f, 0.f, 0.f, 0.f);
            float4 v1 = v0;
            if (gm < N_NODES) {
                const float* p = A + (size_t)gm * IN_F + k0 + aq * 8;
                v0 = *(const float4*)p;
                v1 = *(const float4*)(p + 4);
            }
            bf16x8 b;
            b[0] = bf16rne(v0.x); b[1] = bf16rne(v0.y);
            b[2] = bf16rne(v0.z); b[3] = bf16rne(v0.w);
            b[4] = bf16rne(v1.x); b[5] = bf16rne(v1.y);
            b[6] = bf16rne(v1.z); b[7] = bf16rne(v1.w);
            *(bf16x8*)&As[ar * ASTRIDE + aq * 8] = b;
        }
        {
            const short* src = Wt + (size_t)bn * IN_F + k0 + bh * 16;
            bf16x8 w0 = *(const bf16x8*)(src + 0);
            bf16x8 w1 = *(const bf16x8*)(src + 8);
            short* dst = &Bs[bn * BSTRIDE + bh * 16];
            *(bf16x8*)(dst + 0) = w0;
            *(bf16x8*)(dst + 8) = w1;
        }
        __syncthreads();

        bf16x8 af[4], bf[4];
#pragma unroll
        for (int mt = 0; mt < 4; ++mt)
            af[mt] = *(const bf16x8*)&As[(wrow + mt * 16 + l16) * ASTRIDE + quad * 8];
#pragma unroll
        for (int nt = 0; nt < 4; ++nt)
            bf[nt] = *(const bf16x8*)&Bs[(wcol + nt * 16 + l16) * BSTRIDE + quad * 8];

#pragma unroll
        for (int mt = 0; mt < 4; ++mt)
#pragma unroll
            for (int nt = 0; nt < 4; ++nt)
                acc[mt][nt] = __builtin_amdgcn_mfma_f32_16x16x32_bf16(
                    af[mt], bf[nt], acc[mt][nt], 0, 0, 0);
        __syncthreads();
    }

    // ---- fused per-row int8 quantization epilogue ----
    float pm[4][4];                          // [mt][i]
#pragma unroll
    for (int mt = 0; mt < 4; ++mt)
#pragma unroll
        for (int i = 0; i < 4; ++i) {
            float m = fabsf(acc[mt][0][i]);
            m = fmaxf(m, fabsf(acc[mt][1][i]));
            m = fmaxf(m, fabsf(acc[mt][2][i]));
            m = fmaxf(m, fabsf(acc[mt][3][i]));
            pm[mt][i] = m;
        }
#pragma unroll
    for (int off = 1; off < 16; off <<= 1)
#pragma unroll
        for (int mt = 0; mt < 4; ++mt)
#pragma unroll
            for (int i = 0; i < 4; ++i)
                pm[mt][i] = fmaxf(pm[mt][i], __shfl_xor(pm[mt][i], off, 64));

    if (l16 == 0) {
#pragma unroll
        for (int mt = 0; mt < 4; ++mt)
#pragma unroll
            for (int i = 0; i < 4; ++i)
                redmax[wrow + mt * 16 + quad * 4 + i][wave & 3] = pm[mt][i];
    }
    __syncthreads();

#pragma unroll
    for (int mt = 0; mt < 4; ++mt) {
#pragma unroll
        for (int i = 0; i < 4; ++i) {
            const int rl  = wrow + mt * 16 + quad * 4 + i;
            const int row = m0 + rl;
            if (row < N_NODES) {
                const float m = fmaxf(fmaxf(redmax[rl][0], redmax[rl][1]),
                                      fmaxf(redmax[rl][2], redmax[rl][3]));
                const float inv = (m > 0.f) ? 127.f / m : 0.f;
#pragma unroll
                for (int nt = 0; nt < 4; ++nt) {
                    const int q = (int)rintf(acc[mt][nt][i] * inv) + 128;
                    Cb8[(size_t)row * OUT_F + wcol + nt * 16 + l16] = (unsigned char)q;
                }
                if ((wave & 3) == 0 && l16 == 0)
                    scales[row] = m * (1.f / 127.f);
            }
        }
    }
}

// ---------------------------------------------------------------------------
// Two-pass edge sort (391 buckets x 128 rows), consolidated (R9).
// sortB folds the support row-scale into the edge value:
//   ecv = col<<16 | bf16(val * scales[col])
// ---------------------------------------------------------------------------
__global__ __launch_bounds__(256) void zero_bins_kernel(int* __restrict__ binCounts,
                                                        int* __restrict__ relCur) {
    int i = blockIdx.x * 256 + threadIdx.x;
    if (i < NBINS) { binCounts[i] = 0; relCur[i] = 0; }
}

__global__ __launch_bounds__(256) void histA_kernel(const int* __restrict__ rows,
                                                    int* __restrict__ binCounts) {
    __shared__ int lh[NBINS];
    const int tid = threadIdx.x;
    for (int i = tid; i < NBINS; i += 256) lh[i] = 0;
    __syncthreads();
    for (int i = blockIdx.x * 256 + tid; i < N_EDGES; i += gridDim.x * 256)
        atomicAdd(&lh[rows[i] >> 7], 1);
    __syncthreads();
    for (int i = tid; i < NBINS; i += 256)
        if (lh[i]) atomicAdd(&binCounts[i], lh[i]);
}

__global__ __launch_bounds__(256) void fillA_kernel(const int* __restrict__ rows,
                                                    const int* __restrict__ cols,
                                                    const float* __restrict__ vals,
                                                    const int* __restrict__ binCounts,
                                                    int* __restrict__ relCur,
                                                    int* __restrict__ binStart,
                                                    int2* __restrict__ binned) {
    __shared__ int lhist[NBINS];
    __shared__ int lexcl[NBINS];
    __shared__ int gbase[NBINS];
    __shared__ ull stmp2[256];
    __shared__ int2 lstage[BATCH];
    __shared__ unsigned short sbucket[BATCH];

    const int tid   = threadIdx.x;
    const int start = blockIdx.x * BATCH;
    const int count = min(BATCH, N_EDGES - start);

    for (int i = tid; i < NBINS; i += 256) lhist[i] = 0;
    __syncthreads();

    int myrow[EPT], myrank[EPT];
#pragma unroll
    for (int j = 0; j < EPT; ++j) {
        const int s = j * 256 + tid;
        if (s < count) {
            const int r = rows[start + s];
            myrow[j]  = r;
            myrank[j] = atomicAdd(&lhist[r >> 7], 1);
        }
    }
    __syncthreads();

    // dual pair-scan: high 32b = binCounts prefix (global), low 32b = lhist
    // prefix (local). Low total <= BATCH so no carry into high field.
    {
        const int i0 = 2 * tid, i1 = 2 * tid + 1;
        const int h0 = (i0 < NBINS) ? lhist[i0] : 0;
        const int h1 = (i1 < NBINS) ? lhist[i1] : 0;
        const int c0 = (i0 < NBINS) ? binCounts[i0] : 0;
        const int c1 = (i1 < NBINS) ? binCounts[i1] : 0;
        const ull pair = ((ull)(unsigned)(c0 + c1) << 32) | (unsigned)(h0 + h1);
        stmp2[tid] = pair;
        for (int off = 1; off < 256; off <<= 1) {
            __syncthreads();
            ull t = (tid >= off) ? stmp2[tid - off] : 0ull;
            __syncthreads();
            stmp2[tid] += t;
        }
        __syncthreads();
        const ull pex  = stmp2[tid] - pair;
        const int lex0 = (int)(pex & 0xffffffffull);
        const int bst0 = (int)(pex >> 32);
        if (i0 < NBINS) {
            lexcl[i0] = lex0;
            gbase[i0] = bst0 + (h0 ? atomicAdd(&relCur[i0], h0) : 0);
            if (blockIdx.x == 0) binStart[i0] = bst0;
        }
        if (i1 < NBINS) {
            lexcl[i1] = lex0 + h0;
            gbase[i1] = (bst0 + c0) + (h1 ? atomicAdd(&relCur[i1], h1) : 0);
            if (blockIdx.x == 0) binStart[i1] = bst0 + c0;
        }
    }
    __syncthreads();

    // stage into LDS ordered by bucket
#pragma unroll
    for (int j = 0; j < EPT; ++j) {
        const int s = j * 256 + tid;
        if (s < count) {
            const int r   = myrow[j];
            const int b   = r >> 7;
            const int pos = lexcl[b] + myrank[j];
            lstage[pos]  = make_int2(((r & 127) << 16) | cols[start + s],
                                     __float_as_int(vals[start + s]));
            sbucket[pos] = (unsigned short)b;
        }
    }
    __syncthreads();

    // write out: bucket runs contiguous
#pragma unroll
    for (int j = 0; j < EPT; ++j) {
        const int s = j * 256 + tid;
        if (s < count) {
            const int b = sbucket[s];
            binned[gbase[b] + (s - lexcl[b])] = lstage[s];
        }
    }
}

__global__ __launch_bounds__(512) void sortB_kernel(const int2* __restrict__ binned,
                                                    const int* __restrict__ binStart,
                                                    const int* __restrict__ binCounts,
                                                    const float* __restrict__ scales,
                                                    int* __restrict__ excl,
                                                    unsigned int* __restrict__ ecv) {
    __shared__ int lhist[BROWS];
    __shared__ int lcur[BROWS];

    const int tid  = threadIdx.x;
    const int b    = blockIdx.x;
    const int base = binStart[b];
    const int cnt  = binCounts[b];

    if (tid < BROWS) lhist[tid] = 0;
    __syncthreads();

    for (int i = tid; i < cnt; i += 512)
        atomicAdd(&lhist[binned[base + i].x >> 16], 1);
    __syncthreads();

    // scan 128 with first 128 threads (Hillis-Steele in lcur as temp)
    if (tid < BROWS) lcur[tid] = lhist[tid];
    for (int off = 1; off < BROWS; off <<= 1) {
        __syncthreads();
        int t = (tid >= off && tid < BROWS) ? lcur[tid - off] : 0;
        __syncthreads();
        if (tid < BROWS) lcur[tid] += t;
    }
    __syncthreads();
    if (tid < BROWS) {
        const int pexcl = lcur[tid] - lhist[tid];
        const int row   = b * BROWS + tid;
        lcur[tid] = pexcl;
        if (row < N_NODES) excl[row] = base + pexcl;
    }
    __syncthreads();

    for (int i = tid; i < cnt; i += 512) {
        const int2 e  = binned[base + i];
        const int rl  = e.x >> 16;
        const int col = e.x & 0xFFFF;
        const int rank = atomicAdd(&lcur[rl], 1);
        const float vs = __int_as_float(e.y) * scales[col];   // fold row scale
        ecv[base + rank] = ((unsigned int)col << 16) |
                           (unsigned short)bf16rne(vs);
    }
}

// ---------------------------------------------------------------------------
// Gather, int8 support, SCALAR-PIPE edge stream (R14).
// start/end readfirstlane'd -> compiler emits s_load for ecv[e] (SMEM path,
// off the VMEM queue), col/val extraction + support base address + csum on
// SALU. VALU per edge: 4x v_cvt_f32_ubyte + 4x v_fmac (SGPR src0) + 1 csum.
// Support load: global_load_dword v, v_laneoff, s[base] — no VALU addr math.
// ---------------------------------------------------------------------------
__global__ __launch_bounds__(256) void gather_kernel(const unsigned int* __restrict__ support,
                                                     const int* __restrict__ excl,
                                                     const unsigned int* __restrict__ ecv,
                                                     float4* __restrict__ out) {
    const int tid  = threadIdx.x;
    const int row  = blockIdx.x * 4 + (tid >> 6);
    const int lane = tid & 63;
    if (row >= N_NODES) return;

    int start = excl[row];
    int end   = (row + 1 < N_NODES) ? excl[row + 1] : N_EDGES;
    start = __builtin_amdgcn_readfirstlane(start);   // wave-uniform -> SGPR
    end   = __builtin_amdgcn_readfirstlane(end);

    const char* supbase = (const char*)support;      // scalar 64-bit base
    const unsigned vo = (unsigned)lane * 4u;         // per-lane byte offset

    float4 acc = make_float4(0.f, 0.f, 0.f, 0.f);
    float csum = 0.f;
    int e = start;
    const int end4 = start + ((end - start) & ~3);
    for (; e < end4; e += 4) {
        const unsigned p0 = ecv[e];                  // uniform -> s_load
        const unsigned p1 = ecv[e + 1];
        const unsigned p2 = ecv[e + 2];
        const unsigned p3 = ecv[e + 3];
        const unsigned u0 = *(const unsigned*)(supbase + (((size_t)(p0 >> 16) << 8) + vo));
        const unsigned u1 = *(const unsigned*)(supbase + (((size_t)(p1 >> 16) << 8) + vo));
        const unsigned u2 = *(const unsigned*)(supbase + (((size_t)(p2 >> 16) << 8) + vo));
        const unsigned u3 = *(const unsigned*)(supbase + (((size_t)(p3 >> 16) << 8) + vo));
        const float v0 = b2f((unsigned short)(p0 & 0xFFFF));   // scalar ops
        const float v1 = b2f((unsigned short)(p1 & 0xFFFF));
        const float v2 = b2f((unsigned short)(p2 & 0xFFFF));
        const float v3 = b2f((unsigned short)(p3 & 0xFFFF));
        csum += v0 + v1 + v2 + v3;
        acc.x += v0 * (float)(u0 & 0xff)         + v1 * (float)(u1 & 0xff)
               + v2 * (float)(u2 & 0xff)         + v3 * (float)(u3 & 0xff);
        acc.y += v0 * (float)((u0 >> 8) & 0xff)  + v1 * (float)((u1 >> 8) & 0xff)
               + v2 * (float)((u2 >> 8) & 0xff)  + v3 * (float)((u3 >> 8) & 0xff);
        acc.z += v0 * (float)((u0 >> 16) & 0xff) + v1 * (float)((u1 >> 16) & 0xff)
               + v2 * (float)((u2 >> 16) & 0xff) + v3 * (float)((u3 >> 16) & 0xff);
        acc.w += v0 * (float)(u0 >> 24)          + v1 * (float)(u1 >> 24)
               + v2 * (float)(u2 >> 24)          + v3 * (float)(u3 >> 24);
    }
    for (; e < end; ++e) {
        const unsigned p0 = ecv[e];
        const unsigned u0 = *(const unsigned*)(supbase + (((size_t)(p0 >> 16) << 8) + vo));
        const float v0 = b2f((unsigned short)(p0 & 0xFFFF));
        csum += v0;
        acc.x += v0 * (float)(u0 & 0xff);
        acc.y += v0 * (float)((u0 >> 8) & 0xff);
        acc.z += v0 * (float)((u0 >> 16) & 0xff);
        acc.w += v0 * (float)(u0 >> 24);
    }

    const float bias = 128.f * csum;
    acc.x = fmaxf(acc.x - bias, 0.f);
    acc.y = fmaxf(acc.y - bias, 0.f);
    acc.z = fmaxf(acc.z - bias, 0.f);
    acc.w = fmaxf(acc.w - bias, 0.f);
    out[(size_t)row * 64 + lane] = acc;
}

extern "C" void kernel_launch(void* const* d_in, const int* in_sizes, int n_in,
                              void* d_out, int out_size, void* d_ws, size_t ws_size,
                              hipStream_t stream) {
    const float* features  = (const float*)d_in[0];   // [50000, 512]
    const float* weight    = (const float*)d_in[1];   // [512, 256]
    const float* edge_vals = (const float*)d_in[2];   // [1.6M]
    const int*   edge_rows = (const int*)d_in[3];
    const int*   edge_cols = (const int*)d_in[4];
    float* out = (float*)d_out;                       // [50000, 256]

    // workspace layout (8B-aligned chunks first)  — total ~32.7 MB
    unsigned int* support_i8 = (unsigned int*)d_ws;                     // 12.8 MB
    int2*  binned    = (int2*)(support_i8 + (size_t)N_NODES * 64);      // 12.8 MB
    unsigned int* ecv = (unsigned int*)(binned + N_EDGES);              // 6.4 MB
    int*   excl      = (int*)(ecv + N_EDGES);                           // 50000
    int*   binCounts = excl + N_NODES;                                  // 512
    int*   binStart  = binCounts + 512;                                 // 512
    int*   relCur    = binStart + 512;                                  // 512
    float* scales    = (float*)(relCur + 512);                          // 50000 f32
    short* Wt        = (short*)(scales + N_NODES);                      // 131072 bf16

    // 1) weight transpose + bf16 convert
    wt_kernel<<<(IN_F * OUT_F + 255) / 256, 256, 0, stream>>>(weight, Wt);

    // 2) fused MFMA GEMM + per-row int8 quantization (writes sup8 + scales)
    gemm_mfma_kernel<<<(N_NODES + 127) / 128, 512, 0, stream>>>(
        features, Wt, (unsigned char*)support_i8, scales);

    // 3) two-pass edge sort; sortB folds scales[col] into the edge value
    zero_bins_kernel<<<2, 256, 0, stream>>>(binCounts, relCur);
    histA_kernel<<<256, 256, 0, stream>>>(edge_rows, binCounts);
    fillA_kernel<<<NBATCHES, 256, 0, stream>>>(edge_rows, edge_cols, edge_vals,
                                               binCounts, relCur, binStart, binned);
    sortB_kernel<<<NBINS, 512, 0, stream>>>(binned, binStart, binCounts, scales,
                                            excl, ecv);

    // 4) gather + fused ReLU (one wave per row, int8 support, scalar edges)
    gather_kernel<<<(N_NODES + 3) / 4, 256, 0, stream>>>(
        support_i8, excl, ecv, (float4*)out);
}